// Round 1
// baseline (1335.388 us; speedup 1.0000x reference)
//
#include <hip/hip_runtime.h>
#include <math.h>

#define NN   65536      // total nodes
#define NPER 1024       // nodes per graph
#define NE   1048576    // edges
#define NB   64         // graphs

// ---------------- CSR build ----------------

__global__ __launch_bounds__(256) void count_kernel(const int* __restrict__ ei, int* __restrict__ cnt){
  int e = blockIdx.x*256 + threadIdx.x;
  if (e < NE) atomicAdd(&cnt[ei[NE + e]], 1);
}

__global__ __launch_bounds__(1024) void scan_kernel(const int* __restrict__ cnt, int* __restrict__ off){
  __shared__ int tmp[1024];
  __shared__ int carry;
  int t = threadIdx.x;
  if (t == 0) carry = 0;
  __syncthreads();
  for (int base = 0; base < NN; base += 1024){
    int v = cnt[base + t];
    tmp[t] = v;
    __syncthreads();
    for (int o = 1; o < 1024; o <<= 1){
      int add = (t >= o) ? tmp[t - o] : 0;
      __syncthreads();
      tmp[t] += add;
      __syncthreads();
    }
    off[base + t] = carry + tmp[t] - v;   // exclusive
    __syncthreads();
    if (t == 1023) carry += tmp[1023];
    __syncthreads();
  }
  if (t == 0) off[NN] = carry;
}

__global__ __launch_bounds__(256) void copy_kernel(const int* __restrict__ src, int* __restrict__ dst, int n){
  int i = blockIdx.x*256 + threadIdx.x;
  if (i < n) dst[i] = src[i];
}

__global__ __launch_bounds__(256) void fill_kernel(const int* __restrict__ ei, int* cursor, int* __restrict__ adj){
  int e = blockIdx.x*256 + threadIdx.x;
  if (e < NE){
    int pos = atomicAdd(&cursor[ei[NE + e]], 1);
    adj[pos] = ei[e];
  }
}

// ---------------- aggregation (segment_sum of x[src] into dst rows) ----------------
// one wave per node; dead dst rows skipped (their conv output is masked later);
// dead src rows are zero in x so they contribute nothing.

__global__ __launch_bounds__(256) void gather_kernel(const float* __restrict__ x, int stride, int F,
      const int* __restrict__ off, const int* __restrict__ adj, float* __restrict__ agg,
      const int* __restrict__ alive){
  int w = (blockIdx.x*256 + threadIdx.x) >> 6;
  int lane = threadIdx.x & 63;
  if (w >= NN) return;
  if (alive && !alive[w]) return;
  int s0 = off[w], s1 = off[w+1];
  float a0 = 0.f, a1 = 0.f;
  for (int e = s0; e < s1; ++e){
    const float* xr = x + (size_t)adj[e]*stride;
    a0 += xr[lane];
    if (F > 64) a1 += xr[lane + 64];
  }
  agg[(size_t)w*128 + lane] = a0;
  if (F > 64) agg[(size_t)w*128 + 64 + lane] = a1;
}

// ---------------- conv: y = relu(x@Wr + agg@Wn + b), fused score = y . phat ----------------
// 64 rows x 128 cols per block, 256 threads, each thread 8 rows x 4 cols.
// NOTE: yout aliases aggb (in-place over the same rows): all global reads of agg rows
// happen in the staging loops before the barrier; the epilogue write comes after.

__global__ __launch_bounds__(256) void conv_kernel(const float* __restrict__ xsrc, int strideX, int Kx,
      const float* __restrict__ Wr, const float* aggb, int Ka, const float* __restrict__ Wn,
      const float* __restrict__ bias, const float* __restrict__ phat,
      float* yout, float* __restrict__ score){
  __shared__ float xs[64][64];
  __shared__ float ws[64][128];
  int tid = threadIdx.x;
  int row0 = blockIdx.x * 64;
  int jb = (tid & 31) * 4;
  int rb = (tid >> 5) * 8;
  float acc[8][4];
  #pragma unroll
  for (int r = 0; r < 8; ++r)
    #pragma unroll
    for (int c = 0; c < 4; ++c) acc[r][c] = 0.f;

  for (int phase = 0; phase < 2; ++phase){
    const float* X = phase ? aggb : xsrc;
    int stride    = phase ? 128  : strideX;
    int K         = phase ? Ka   : Kx;
    const float* W = phase ? Wn  : Wr;
    for (int kc = 0; kc < K; kc += 64){
      __syncthreads();
      #pragma unroll
      for (int t2 = 0; t2 < 16; ++t2){
        int f = tid + t2*256; int r = f >> 6, kk = f & 63;
        xs[r][kk] = X[(size_t)(row0 + r)*stride + kc + kk];
      }
      #pragma unroll
      for (int t2 = 0; t2 < 32; ++t2){
        int f = tid + t2*256; int kk = f >> 7, j = f & 127;
        ws[kk][j] = W[(size_t)(kc + kk)*128 + j];
      }
      __syncthreads();
      #pragma unroll 16
      for (int kk = 0; kk < 64; ++kk){
        float4 wv = *(const float4*)&ws[kk][jb];
        #pragma unroll
        for (int r = 0; r < 8; ++r){
          float xv = xs[rb + r][kk];
          acc[r][0] = fmaf(xv, wv.x, acc[r][0]);
          acc[r][1] = fmaf(xv, wv.y, acc[r][1]);
          acc[r][2] = fmaf(xv, wv.z, acc[r][2]);
          acc[r][3] = fmaf(xv, wv.w, acc[r][3]);
        }
      }
    }
  }

  float4 bv = *(const float4*)&bias[jb];
  float4 pv = *(const float4*)&phat[jb];
  #pragma unroll
  for (int r = 0; r < 8; ++r){
    int row = row0 + rb + r;
    float4 o;
    o.x = fmaxf(acc[r][0] + bv.x, 0.f);
    o.y = fmaxf(acc[r][1] + bv.y, 0.f);
    o.z = fmaxf(acc[r][2] + bv.z, 0.f);
    o.w = fmaxf(acc[r][3] + bv.w, 0.f);
    *(float4*)&yout[(size_t)row*128 + jb] = o;
    float part = o.x*pv.x + o.y*pv.y + o.z*pv.z + o.w*pv.w;
    #pragma unroll
    for (int m = 16; m >= 1; m >>= 1) part += __shfl_xor(part, m);
    if ((tid & 31) == 0) score[row] = part;
  }
}

// ---------------- p / ||p|| ----------------

__global__ __launch_bounds__(128) void prep_kernel(const float* __restrict__ p, float* __restrict__ phat){
  __shared__ float red[128];
  int t = threadIdx.x;
  float v = p[t];
  red[t] = v*v;
  __syncthreads();
  for (int s = 64; s > 0; s >>= 1){
    if (t < s) red[t] += red[t + s];
    __syncthreads();
  }
  phat[t] = v / sqrtf(red[0]);
}

// ---------------- per-graph top-k via bitonic sort of (score desc, idx asc) ----------------

__global__ __launch_bounds__(1024) void topk_kernel(const float* __restrict__ score, const int* __restrict__ alive_cur,
      int* __restrict__ alive_next, float* __restrict__ tanhv, int m){
  __shared__ float sv[1024];
  __shared__ int   si[1024];
  int g = blockIdx.x, t = threadIdx.x;
  int node = g*NPER + t;
  bool ok = alive_cur ? (alive_cur[node] != 0) : true;
  sv[t] = ok ? score[node] : -INFINITY;
  si[t] = node;
  alive_next[node] = 0;
  __syncthreads();
  for (int size = 2; size <= 1024; size <<= 1){
    for (int stride = size >> 1; stride > 0; stride >>= 1){
      int j = t ^ stride;
      if (j > t){
        float vt = sv[t], vj = sv[j];
        int   it = si[t], ij = si[j];
        bool beforeTJ = (vt > vj) || (vt == vj && it < ij);  // t belongs first
        bool ascending = ((t & size) == 0);
        bool dosw = ascending ? !beforeTJ : beforeTJ;
        if (dosw){ sv[t] = vj; sv[j] = vt; si[t] = ij; si[j] = it; }
      }
      __syncthreads();
    }
  }
  if (t < m){
    int idx = si[t];
    alive_next[idx] = 1;
    tanhv[idx] = tanhf(sv[t]);
  }
}

// ---------------- x_next = selected ? y*tanh(s) : 0 ----------------

__global__ __launch_bounds__(256) void apply_kernel(const float4* __restrict__ y, const int* __restrict__ alive,
      const float* __restrict__ tanhv, float4* __restrict__ x){
  int i = blockIdx.x*256 + threadIdx.x;
  if (i >= NN*32) return;
  int node = i >> 5;
  float4 o = make_float4(0.f, 0.f, 0.f, 0.f);
  if (alive[node]){
    float tv = tanhv[node];
    float4 v = y[i];
    o = make_float4(v.x*tv, v.y*tv, v.z*tv, v.w*tv);
  }
  x[i] = o;
}

// ---------------- readout: per-graph masked max + mean, accumulated into h ----------------

__global__ __launch_bounds__(128) void readout_kernel(const float* __restrict__ x, const int* __restrict__ alive,
      float* __restrict__ h, int m){
  int g = blockIdx.x, f = threadIdx.x;
  float mx = -INFINITY, sm = 0.f;
  int base = g*NPER;
  for (int n = 0; n < NPER; ++n){
    if (!alive[base + n]) continue;
    float v = x[(size_t)(base + n)*128 + f];
    mx = fmaxf(mx, v);
    sm += v;
  }
  h[g*256 + f]       += mx;
  h[g*256 + 128 + f] += sm / (float)m;
}

// ---------------- final MLP + log_softmax ----------------

__global__ __launch_bounds__(128) void final_kernel(const float* __restrict__ h,
      const float* __restrict__ l1w, const float* __restrict__ l1b,
      const float* __restrict__ l2w, const float* __restrict__ l2b,
      float* __restrict__ out){
  int g = blockIdx.x, t = threadIdx.x;
  __shared__ float hrow[256];
  __shared__ float red0[128], red1[128];
  hrow[t]       = h[g*256 + t];
  hrow[t + 128] = h[g*256 + 128 + t];
  __syncthreads();
  float a = l1b[t];
  for (int k = 0; k < 256; ++k) a = fmaf(hrow[k], l1w[k*128 + t], a);
  a = fmaxf(a, 0.f);
  red0[t] = a * l2w[t*2 + 0];
  red1[t] = a * l2w[t*2 + 1];
  __syncthreads();
  for (int s = 64; s > 0; s >>= 1){
    if (t < s){ red0[t] += red0[t + s]; red1[t] += red1[t + s]; }
    __syncthreads();
  }
  if (t == 0){
    float z0 = fmaxf(red0[0] + l2b[0], 0.f);
    float z1 = fmaxf(red1[0] + l2b[1], 0.f);
    float mz = fmaxf(z0, z1);
    float lse = mz + logf(expf(z0 - mz) + expf(z1 - mz));
    out[g*2 + 0] = z0 - lse;
    out[g*2 + 1] = z1 - lse;
  }
}

// ---------------- host ----------------

static inline size_t alignup(size_t x){ return (x + 255) & ~(size_t)255; }

extern "C" void kernel_launch(void* const* d_in, const int* in_sizes, int n_in,
                              void* d_out, int out_size, void* d_ws, size_t ws_size,
                              hipStream_t stream) {
  const float* x_in = (const float*)d_in[0];
  const int*   ei   = (const int*)d_in[1];
  const float* Wr[3] = {(const float*)d_in[3], (const float*)d_in[6], (const float*)d_in[9]};
  const float* Wn[3] = {(const float*)d_in[4], (const float*)d_in[7], (const float*)d_in[10]};
  const float* bs[3] = {(const float*)d_in[5], (const float*)d_in[8], (const float*)d_in[11]};
  const float* ps[3] = {(const float*)d_in[12], (const float*)d_in[13], (const float*)d_in[14]};
  const float* l1w = (const float*)d_in[15];
  const float* l1b = (const float*)d_in[16];
  const float* l2w = (const float*)d_in[17];
  const float* l2b = (const float*)d_in[18];
  float* out = (float*)d_out;

  char* w = (char*)d_ws;
  size_t o = 0;
  auto take = [&](size_t bytes) -> void* { void* p = w + o; o = alignup(o + bytes); return p; };
  int*   off    = (int*)  take((size_t)(NN + 1) * 4);
  int*   adj    = (int*)  take((size_t)NE * 4);
  int*   cnt    = (int*)  take((size_t)NN * 4);     // reused as cursor
  int*   aliveA = (int*)  take((size_t)NN * 4);
  int*   aliveB = (int*)  take((size_t)NN * 4);
  float* tanhv  = (float*)take((size_t)NN * 4);
  float* score  = (float*)take((size_t)NN * 4);
  float* phat   = (float*)take(128 * 4);
  float* h      = (float*)take((size_t)NB * 256 * 4);
  float* A      = (float*)take((size_t)NN * 128 * 4);  // node features (current level)
  float* Bb     = (float*)take((size_t)NN * 128 * 4);  // agg, then conv output y
  (void)ws_size; (void)n_in; (void)in_sizes; (void)out_size;

  // CSR build (by dst, storing src)
  hipMemsetAsync(cnt, 0, (size_t)NN * 4, stream);
  count_kernel<<<NE/256, 256, 0, stream>>>(ei, cnt);
  scan_kernel<<<1, 1024, 0, stream>>>(cnt, off);
  copy_kernel<<<(NN + 255)/256, 256, 0, stream>>>(off, cnt, NN);
  fill_kernel<<<NE/256, 256, 0, stream>>>(ei, cnt, adj);
  hipMemsetAsync(h, 0, (size_t)NB * 256 * 4, stream);

  const int MS[3] = {820, 656, 525};
  int* aliveCur = nullptr;
  int* aliveNext = aliveA;
  for (int l = 0; l < 3; ++l){
    prep_kernel<<<1, 128, 0, stream>>>(ps[l], phat);
    if (l == 0){
      gather_kernel<<<NN*64/256, 256, 0, stream>>>(x_in, 64, 64, off, adj, Bb, nullptr);
      conv_kernel<<<NN/64, 256, 0, stream>>>(x_in, 64, 64, Wr[0], Bb, 64, Wn[0], bs[0], phat, Bb, score);
    } else {
      gather_kernel<<<NN*64/256, 256, 0, stream>>>(A, 128, 128, off, adj, Bb, aliveCur);
      conv_kernel<<<NN/64, 256, 0, stream>>>(A, 128, 128, Wr[l], Bb, 128, Wn[l], bs[l], phat, Bb, score);
    }
    topk_kernel<<<NB, 1024, 0, stream>>>(score, aliveCur, aliveNext, tanhv, MS[l]);
    apply_kernel<<<NN*32/256, 256, 0, stream>>>((const float4*)Bb, aliveNext, tanhv, (float4*)A);
    readout_kernel<<<NB, 128, 0, stream>>>(A, aliveNext, h, MS[l]);
    aliveCur = aliveNext;
    aliveNext = (l == 0) ? aliveB : aliveA;
  }
  final_kernel<<<NB, 128, 0, stream>>>(h, l1w, l1b, l2w, l2b, out);
}

// Round 2
// 737.184 us; speedup vs baseline: 1.8115x; 1.8115x over previous
//
#include <hip/hip_runtime.h>
#include <math.h>

#define NN   65536      // total nodes
#define NPER 1024       // nodes per graph
#define NE   1048576    // edges
#define NB   64         // graphs

// ---------------- CSR build ----------------

__global__ __launch_bounds__(256) void count_kernel(const int* __restrict__ ei, int* __restrict__ cnt){
  int e = blockIdx.x*256 + threadIdx.x;
  if (e < NE) atomicAdd(&cnt[ei[NE + e]], 1);
}

__global__ __launch_bounds__(1024) void scan_kernel(const int* __restrict__ cnt, int* __restrict__ off){
  __shared__ int tmp[1024];
  __shared__ int carry;
  int t = threadIdx.x;
  if (t == 0) carry = 0;
  __syncthreads();
  for (int base = 0; base < NN; base += 1024){
    int v = cnt[base + t];
    tmp[t] = v;
    __syncthreads();
    for (int o = 1; o < 1024; o <<= 1){
      int add = (t >= o) ? tmp[t - o] : 0;
      __syncthreads();
      tmp[t] += add;
      __syncthreads();
    }
    off[base + t] = carry + tmp[t] - v;   // exclusive
    __syncthreads();
    if (t == 1023) carry += tmp[1023];
    __syncthreads();
  }
  if (t == 0) off[NN] = carry;
}

__global__ __launch_bounds__(256) void copy_kernel(const int* __restrict__ src, int* __restrict__ dst, int n){
  int i = blockIdx.x*256 + threadIdx.x;
  if (i < n) dst[i] = src[i];
}

__global__ __launch_bounds__(256) void fill_kernel(const int* __restrict__ ei, int* cursor, int* __restrict__ adj){
  int e = blockIdx.x*256 + threadIdx.x;
  if (e < NE){
    int pos = atomicAdd(&cursor[ei[NE + e]], 1);
    adj[pos] = ei[e];
  }
}

// ---------------- aggregation (segment_sum of x[src] into dst rows) ----------------

__global__ __launch_bounds__(256) void gather_kernel(const float* __restrict__ x, int stride, int F,
      const int* __restrict__ off, const int* __restrict__ adj, float* __restrict__ agg,
      const int* __restrict__ alive){
  int w = (blockIdx.x*256 + threadIdx.x) >> 6;
  int lane = threadIdx.x & 63;
  if (w >= NN) return;
  if (alive && !alive[w]) return;
  int s0 = off[w], s1 = off[w+1];
  float a0 = 0.f, a1 = 0.f;
  for (int e = s0; e < s1; ++e){
    const float* xr = x + (size_t)adj[e]*stride;
    a0 += xr[lane];
    if (F > 64) a1 += xr[lane + 64];
  }
  agg[(size_t)w*128 + lane] = a0;
  if (F > 64) agg[(size_t)w*128 + 64 + lane] = a1;
}

// ---------------- conv: y = relu(x@Wr + agg@Wn + b), fused score = y . phat ----------------
// 64 rows x 128 cols per block, 256 threads, each thread 8 rows x 4 cols.
// NOTE: yout aliases aggb (in-place over the same rows): all global reads of agg rows
// happen in the staging loops before the barrier; the epilogue write comes after.

__global__ __launch_bounds__(256) void conv_kernel(const float* __restrict__ xsrc, int strideX, int Kx,
      const float* __restrict__ Wr, const float* aggb, int Ka, const float* __restrict__ Wn,
      const float* __restrict__ bias, const float* __restrict__ phat,
      float* yout, float* __restrict__ score){
  __shared__ float xs[64][64];
  __shared__ float ws[64][128];
  int tid = threadIdx.x;
  int row0 = blockIdx.x * 64;
  int jb = (tid & 31) * 4;
  int rb = (tid >> 5) * 8;
  float acc[8][4];
  #pragma unroll
  for (int r = 0; r < 8; ++r)
    #pragma unroll
    for (int c = 0; c < 4; ++c) acc[r][c] = 0.f;

  for (int phase = 0; phase < 2; ++phase){
    const float* X = phase ? aggb : xsrc;
    int stride    = phase ? 128  : strideX;
    int K         = phase ? Ka   : Kx;
    const float* W = phase ? Wn  : Wr;
    for (int kc = 0; kc < K; kc += 64){
      __syncthreads();
      #pragma unroll
      for (int t2 = 0; t2 < 16; ++t2){
        int f = tid + t2*256; int r = f >> 6, kk = f & 63;
        xs[r][kk] = X[(size_t)(row0 + r)*stride + kc + kk];
      }
      #pragma unroll
      for (int t2 = 0; t2 < 32; ++t2){
        int f = tid + t2*256; int kk = f >> 7, j = f & 127;
        ws[kk][j] = W[(size_t)(kc + kk)*128 + j];
      }
      __syncthreads();
      #pragma unroll 16
      for (int kk = 0; kk < 64; ++kk){
        float4 wv = *(const float4*)&ws[kk][jb];
        #pragma unroll
        for (int r = 0; r < 8; ++r){
          float xv = xs[rb + r][kk];
          acc[r][0] = fmaf(xv, wv.x, acc[r][0]);
          acc[r][1] = fmaf(xv, wv.y, acc[r][1]);
          acc[r][2] = fmaf(xv, wv.z, acc[r][2]);
          acc[r][3] = fmaf(xv, wv.w, acc[r][3]);
        }
      }
    }
  }

  float4 bv = *(const float4*)&bias[jb];
  float4 pv = *(const float4*)&phat[jb];
  #pragma unroll
  for (int r = 0; r < 8; ++r){
    int row = row0 + rb + r;
    float4 o;
    o.x = fmaxf(acc[r][0] + bv.x, 0.f);
    o.y = fmaxf(acc[r][1] + bv.y, 0.f);
    o.z = fmaxf(acc[r][2] + bv.z, 0.f);
    o.w = fmaxf(acc[r][3] + bv.w, 0.f);
    *(float4*)&yout[(size_t)row*128 + jb] = o;
    float part = o.x*pv.x + o.y*pv.y + o.z*pv.z + o.w*pv.w;
    #pragma unroll
    for (int m = 16; m >= 1; m >>= 1) part += __shfl_xor(part, m);
    if ((tid & 31) == 0) score[row] = part;
  }
}

// ---------------- p / ||p|| ----------------

__global__ __launch_bounds__(128) void prep_kernel(const float* __restrict__ p, float* __restrict__ phat){
  __shared__ float red[128];
  int t = threadIdx.x;
  float v = p[t];
  red[t] = v*v;
  __syncthreads();
  for (int s = 64; s > 0; s >>= 1){
    if (t < s) red[t] += red[t + s];
    __syncthreads();
  }
  phat[t] = v / sqrtf(red[0]);
}

// ---------------- per-graph top-k via bitonic sort of (score desc, idx asc) ----------------

__global__ __launch_bounds__(1024) void topk_kernel(const float* __restrict__ score, const int* __restrict__ alive_cur,
      int* __restrict__ alive_next, float* __restrict__ tanhv, int m){
  __shared__ float sv[1024];
  __shared__ int   si[1024];
  int g = blockIdx.x, t = threadIdx.x;
  int node = g*NPER + t;
  bool ok = alive_cur ? (alive_cur[node] != 0) : true;
  sv[t] = ok ? score[node] : -INFINITY;
  si[t] = node;
  alive_next[node] = 0;
  __syncthreads();
  for (int size = 2; size <= 1024; size <<= 1){
    for (int stride = size >> 1; stride > 0; stride >>= 1){
      int j = t ^ stride;
      if (j > t){
        float vt = sv[t], vj = sv[j];
        int   it = si[t], ij = si[j];
        bool beforeTJ = (vt > vj) || (vt == vj && it < ij);  // t belongs first
        bool ascending = ((t & size) == 0);
        bool dosw = ascending ? !beforeTJ : beforeTJ;
        if (dosw){ sv[t] = vj; sv[j] = vt; si[t] = ij; si[j] = it; }
      }
      __syncthreads();
    }
  }
  if (t < m){
    int idx = si[t];
    alive_next[idx] = 1;
    tanhv[idx] = tanhf(sv[t]);
  }
}

// ---------------- fused: x = selected ? y*tanh(s) : 0  +  per-graph masked max/mean readout ----------------
// grid (NB, 4): block = (graph g, feature quarter fq). 1024 threads = 32 node-groups x 32 features.
// Each thread reduces 32 nodes; LDS tree-reduce over the 32 groups; h += {max, sum/m}.

__global__ __launch_bounds__(1024) void apply_readout_kernel(const float* __restrict__ y,
      const int* __restrict__ alive, const float* __restrict__ tanhv,
      float* __restrict__ x, float* __restrict__ h, int m){
  __shared__ float smx[32][33];
  __shared__ float ssm[32][33];
  int g = blockIdx.x;
  int fq = blockIdx.y;
  int t = threadIdx.x;
  int c  = t >> 5;         // node group 0..31
  int lf = t & 31;         // feature within quarter
  int f  = fq*32 + lf;
  int base = g*NPER;
  float mx = -INFINITY, sm = 0.f;
  #pragma unroll 4
  for (int i = 0; i < 32; ++i){
    int node = base + c + i*32;
    int al = alive[node];
    float tv = tanhv[node];           // garbage for dead nodes, never used
    float v = y[(size_t)node*128 + f];
    float o = al ? v*tv : 0.f;
    x[(size_t)node*128 + f] = o;
    mx = al ? fmaxf(mx, o) : mx;
    sm += o;
  }
  smx[c][lf] = mx; ssm[c][lf] = sm;
  __syncthreads();
  for (int s = 16; s > 0; s >>= 1){
    if (c < s){
      smx[c][lf] = fmaxf(smx[c][lf], smx[c+s][lf]);
      ssm[c][lf] += ssm[c+s][lf];
    }
    __syncthreads();
  }
  if (c == 0){
    h[g*256 + f]       += smx[0][lf];
    h[g*256 + 128 + f] += ssm[0][lf] / (float)m;
  }
}

// ---------------- final MLP + log_softmax ----------------

__global__ __launch_bounds__(128) void final_kernel(const float* __restrict__ h,
      const float* __restrict__ l1w, const float* __restrict__ l1b,
      const float* __restrict__ l2w, const float* __restrict__ l2b,
      float* __restrict__ out){
  int g = blockIdx.x, t = threadIdx.x;
  __shared__ float hrow[256];
  __shared__ float red0[128], red1[128];
  hrow[t]       = h[g*256 + t];
  hrow[t + 128] = h[g*256 + 128 + t];
  __syncthreads();
  float a = l1b[t];
  for (int k = 0; k < 256; ++k) a = fmaf(hrow[k], l1w[k*128 + t], a);
  a = fmaxf(a, 0.f);
  red0[t] = a * l2w[t*2 + 0];
  red1[t] = a * l2w[t*2 + 1];
  __syncthreads();
  for (int s = 64; s > 0; s >>= 1){
    if (t < s){ red0[t] += red0[t + s]; red1[t] += red1[t + s]; }
    __syncthreads();
  }
  if (t == 0){
    float z0 = fmaxf(red0[0] + l2b[0], 0.f);
    float z1 = fmaxf(red1[0] + l2b[1], 0.f);
    float mz = fmaxf(z0, z1);
    float lse = mz + logf(expf(z0 - mz) + expf(z1 - mz));
    out[g*2 + 0] = z0 - lse;
    out[g*2 + 1] = z1 - lse;
  }
}

// ---------------- host ----------------

static inline size_t alignup(size_t x){ return (x + 255) & ~(size_t)255; }

extern "C" void kernel_launch(void* const* d_in, const int* in_sizes, int n_in,
                              void* d_out, int out_size, void* d_ws, size_t ws_size,
                              hipStream_t stream) {
  const float* x_in = (const float*)d_in[0];
  const int*   ei   = (const int*)d_in[1];
  const float* Wr[3] = {(const float*)d_in[3], (const float*)d_in[6], (const float*)d_in[9]};
  const float* Wn[3] = {(const float*)d_in[4], (const float*)d_in[7], (const float*)d_in[10]};
  const float* bs[3] = {(const float*)d_in[5], (const float*)d_in[8], (const float*)d_in[11]};
  const float* ps[3] = {(const float*)d_in[12], (const float*)d_in[13], (const float*)d_in[14]};
  const float* l1w = (const float*)d_in[15];
  const float* l1b = (const float*)d_in[16];
  const float* l2w = (const float*)d_in[17];
  const float* l2b = (const float*)d_in[18];
  float* out = (float*)d_out;

  char* w = (char*)d_ws;
  size_t o = 0;
  auto take = [&](size_t bytes) -> void* { void* p = w + o; o = alignup(o + bytes); return p; };
  int*   off    = (int*)  take((size_t)(NN + 1) * 4);
  int*   adj    = (int*)  take((size_t)NE * 4);
  int*   cnt    = (int*)  take((size_t)NN * 4);     // reused as cursor
  int*   aliveA = (int*)  take((size_t)NN * 4);
  int*   aliveB = (int*)  take((size_t)NN * 4);
  float* tanhv  = (float*)take((size_t)NN * 4);
  float* score  = (float*)take((size_t)NN * 4);
  float* phat   = (float*)take(128 * 4);
  float* h      = (float*)take((size_t)NB * 256 * 4);
  float* A      = (float*)take((size_t)NN * 128 * 4);  // node features (current level)
  float* Bb     = (float*)take((size_t)NN * 128 * 4);  // agg, then conv output y
  (void)ws_size; (void)n_in; (void)in_sizes; (void)out_size;

  // CSR build (by dst, storing src)
  hipMemsetAsync(cnt, 0, (size_t)NN * 4, stream);
  count_kernel<<<NE/256, 256, 0, stream>>>(ei, cnt);
  scan_kernel<<<1, 1024, 0, stream>>>(cnt, off);
  copy_kernel<<<(NN + 255)/256, 256, 0, stream>>>(off, cnt, NN);
  fill_kernel<<<NE/256, 256, 0, stream>>>(ei, cnt, adj);
  hipMemsetAsync(h, 0, (size_t)NB * 256 * 4, stream);

  const int MS[3] = {820, 656, 525};
  int* aliveCur = nullptr;
  int* aliveNext = aliveA;
  for (int l = 0; l < 3; ++l){
    prep_kernel<<<1, 128, 0, stream>>>(ps[l], phat);
    if (l == 0){
      gather_kernel<<<NN*64/256, 256, 0, stream>>>(x_in, 64, 64, off, adj, Bb, nullptr);
      conv_kernel<<<NN/64, 256, 0, stream>>>(x_in, 64, 64, Wr[0], Bb, 64, Wn[0], bs[0], phat, Bb, score);
    } else {
      gather_kernel<<<NN*64/256, 256, 0, stream>>>(A, 128, 128, off, adj, Bb, aliveCur);
      conv_kernel<<<NN/64, 256, 0, stream>>>(A, 128, 128, Wr[l], Bb, 128, Wn[l], bs[l], phat, Bb, score);
    }
    topk_kernel<<<NB, 1024, 0, stream>>>(score, aliveCur, aliveNext, tanhv, MS[l]);
    apply_readout_kernel<<<dim3(NB, 4), 1024, 0, stream>>>(Bb, aliveNext, tanhv, A, h, MS[l]);
    readout_done:;
    aliveCur = aliveNext;
    aliveNext = (l == 0) ? aliveB : aliveA;
  }
  final_kernel<<<NB, 128, 0, stream>>>(h, l1w, l1b, l2w, l2b, out);
}

// Round 3
// 620.023 us; speedup vs baseline: 2.1538x; 1.1890x over previous
//
#include <hip/hip_runtime.h>
#include <math.h>

#define NN   65536      // total nodes
#define NPER 1024       // nodes per graph
#define NE   1048576    // edges
#define NB   64         // graphs

// ---------------- CSR build ----------------

__global__ __launch_bounds__(256) void count_kernel(const int* __restrict__ ei, int* __restrict__ cnt){
  int e = blockIdx.x*256 + threadIdx.x;
  if (e < NE) atomicAdd(&cnt[ei[NE + e]], 1);
}

// hierarchical exclusive scan of cnt[NN] -> off[NN+1] (+ cursor copy)
__global__ __launch_bounds__(1024) void scan1_kernel(const int* __restrict__ cnt,
      int* __restrict__ loc, int* __restrict__ bsum){
  __shared__ int wsum[16];
  int t = threadIdx.x;
  int i = blockIdx.x*1024 + t;
  int lane = t & 63, wid = t >> 6;
  int v = cnt[i];
  int s = v;
  #pragma unroll
  for (int d = 1; d < 64; d <<= 1){
    int src = (lane >= d) ? (lane - d) : lane;
    int u = __shfl(s, src);
    if (lane >= d) s += u;
  }
  if (lane == 63) wsum[wid] = s;
  __syncthreads();
  if (wid == 0){
    int ws = (lane < 16) ? wsum[lane] : 0;
    #pragma unroll
    for (int d = 1; d < 16; d <<= 1){
      int src = (lane >= d) ? (lane - d) : lane;
      int u = __shfl(ws, src);
      if (lane >= d) ws += u;
    }
    if (lane < 16) wsum[lane] = ws;
  }
  __syncthreads();
  int base = (wid > 0) ? wsum[wid - 1] : 0;
  loc[i] = base + s - v;                 // exclusive within block
  if (t == 1023) bsum[blockIdx.x] = base + s;
}

__global__ __launch_bounds__(64) void scan2_kernel(const int* __restrict__ bsum, int* __restrict__ boff){
  int t = threadIdx.x;
  int v = bsum[t];
  int s = v;
  #pragma unroll
  for (int d = 1; d < 64; d <<= 1){
    int src = (t >= d) ? (t - d) : t;
    int u = __shfl(s, src);
    if (t >= d) s += u;
  }
  boff[t] = s - v;
}

__global__ __launch_bounds__(1024) void scan3_kernel(const int* __restrict__ loc, const int* __restrict__ boff,
      int* __restrict__ off, int* __restrict__ cursor){
  int i = blockIdx.x*1024 + threadIdx.x;
  int v = loc[i] + boff[blockIdx.x];
  off[i] = v;
  cursor[i] = v;
  if (i == NN - 1) off[NN] = NE;
}

__global__ __launch_bounds__(256) void fill_kernel(const int* __restrict__ ei, int* cursor, int* __restrict__ adj){
  int e = blockIdx.x*256 + threadIdx.x;
  if (e < NE){
    int pos = atomicAdd(&cursor[ei[NE + e]], 1);
    adj[pos] = ei[e];
  }
}

// ---------------- aggregation (segment_sum of x[src] into dst rows) ----------------
// one wave per node. F==64: lane owns feature `lane` (scalar loads, 256B/row/instr).
// F==128: lane owns features 2*lane, 2*lane+1 (float2 loads, 512B/row/instr).

__global__ __launch_bounds__(256) void gather_kernel(const float* __restrict__ x, int stride, int F,
      const int* __restrict__ off, const int* __restrict__ adj, float* __restrict__ agg,
      const int* __restrict__ alive){
  int w = (blockIdx.x*256 + threadIdx.x) >> 6;
  int lane = threadIdx.x & 63;
  if (w >= NN) return;
  if (alive && !alive[w]) return;
  int s0 = off[w], s1 = off[w+1];
  if (F == 64){
    float a0 = 0.f;
    for (int e = s0; e < s1; ++e)
      a0 += x[(size_t)adj[e]*stride + lane];
    agg[(size_t)w*128 + lane] = a0;
  } else {
    float a0 = 0.f, a1 = 0.f;
    for (int e = s0; e < s1; ++e){
      float2 v = *(const float2*)(x + (size_t)adj[e]*stride + lane*2);
      a0 += v.x; a1 += v.y;
    }
    *(float2*)&agg[(size_t)w*128 + lane*2] = make_float2(a0, a1);
  }
}

// ---------------- conv: y = relu(x@Wr + agg@Wn + b), fused raw score = y . p ----------------
// 64 rows x 128 cols per block, 256 threads, each thread 8 rows x 4 cols.
// NOTE: yout aliases aggb (in-place over the same rows): all global reads of agg rows
// happen in the staging loops before the barrier; the epilogue write comes after.

__global__ __launch_bounds__(256) void conv_kernel(const float* __restrict__ xsrc, int strideX, int Kx,
      const float* __restrict__ Wr, const float* aggb, int Ka, const float* __restrict__ Wn,
      const float* __restrict__ bias, const float* __restrict__ p,
      float* yout, float* __restrict__ score){
  __shared__ float xs[64][64];
  __shared__ float ws[64][128];
  int tid = threadIdx.x;
  int row0 = blockIdx.x * 64;
  int jb = (tid & 31) * 4;
  int rb = (tid >> 5) * 8;
  float acc[8][4];
  #pragma unroll
  for (int r = 0; r < 8; ++r)
    #pragma unroll
    for (int c = 0; c < 4; ++c) acc[r][c] = 0.f;

  for (int phase = 0; phase < 2; ++phase){
    const float* X = phase ? aggb : xsrc;
    int stride    = phase ? 128  : strideX;
    int K         = phase ? Ka   : Kx;
    const float* W = phase ? Wn  : Wr;
    for (int kc = 0; kc < K; kc += 64){
      __syncthreads();
      #pragma unroll
      for (int t2 = 0; t2 < 16; ++t2){
        int f = tid + t2*256; int r = f >> 6, kk = f & 63;
        xs[r][kk] = X[(size_t)(row0 + r)*stride + kc + kk];
      }
      #pragma unroll
      for (int t2 = 0; t2 < 32; ++t2){
        int f = tid + t2*256; int kk = f >> 7, j = f & 127;
        ws[kk][j] = W[(size_t)(kc + kk)*128 + j];
      }
      __syncthreads();
      #pragma unroll 16
      for (int kk = 0; kk < 64; ++kk){
        float4 wv = *(const float4*)&ws[kk][jb];
        #pragma unroll
        for (int r = 0; r < 8; ++r){
          float xv = xs[rb + r][kk];
          acc[r][0] = fmaf(xv, wv.x, acc[r][0]);
          acc[r][1] = fmaf(xv, wv.y, acc[r][1]);
          acc[r][2] = fmaf(xv, wv.z, acc[r][2]);
          acc[r][3] = fmaf(xv, wv.w, acc[r][3]);
        }
      }
    }
  }

  float4 bv = *(const float4*)&bias[jb];
  float4 pv = *(const float4*)&p[jb];
  #pragma unroll
  for (int r = 0; r < 8; ++r){
    int row = row0 + rb + r;
    float4 o;
    o.x = fmaxf(acc[r][0] + bv.x, 0.f);
    o.y = fmaxf(acc[r][1] + bv.y, 0.f);
    o.z = fmaxf(acc[r][2] + bv.z, 0.f);
    o.w = fmaxf(acc[r][3] + bv.w, 0.f);
    *(float4*)&yout[(size_t)row*128 + jb] = o;
    float part = o.x*pv.x + o.y*pv.y + o.z*pv.z + o.w*pv.w;
    #pragma unroll
    for (int m = 16; m >= 1; m >>= 1) part += __shfl_xor(part, m);
    if ((tid & 31) == 0) score[row] = part;
  }
}

// ---------------- per-graph top-k via bitonic sort of (raw score desc, idx asc) ----------------
// ordering is invariant to the positive scale 1/||p||; apply it only inside tanh.

__global__ __launch_bounds__(1024) void topk_kernel(const float* __restrict__ score, const int* __restrict__ alive_cur,
      int* __restrict__ alive_next, float* __restrict__ tanhv, const float* __restrict__ p, int m){
  __shared__ float sv[1024];
  __shared__ int   si[1024];
  __shared__ float rnorm;
  int g = blockIdx.x, t = threadIdx.x;
  if (t < 64){
    float v0 = p[t], v1 = p[t + 64];
    float ss = v0*v0 + v1*v1;
    #pragma unroll
    for (int mm = 32; mm >= 1; mm >>= 1) ss += __shfl_xor(ss, mm);
    if (t == 0) rnorm = rsqrtf(ss);
  }
  int node = g*NPER + t;
  bool ok = alive_cur ? (alive_cur[node] != 0) : true;
  sv[t] = ok ? score[node] : -INFINITY;
  si[t] = node;
  alive_next[node] = 0;
  __syncthreads();
  for (int size = 2; size <= 1024; size <<= 1){
    for (int stride = size >> 1; stride > 0; stride >>= 1){
      int j = t ^ stride;
      if (j > t){
        float vt = sv[t], vj = sv[j];
        int   it = si[t], ij = si[j];
        bool beforeTJ = (vt > vj) || (vt == vj && it < ij);  // t belongs first
        bool ascending = ((t & size) == 0);
        bool dosw = ascending ? !beforeTJ : beforeTJ;
        if (dosw){ sv[t] = vj; sv[j] = vt; si[t] = ij; si[j] = it; }
      }
      __syncthreads();
    }
  }
  if (t < m){
    int idx = si[t];
    alive_next[idx] = 1;
    tanhv[idx] = tanhf(sv[t] * rnorm);
  }
}

// ---------------- fused: x = selected ? y*tanh(s) : 0  +  per-graph masked max/mean readout ----------------
// grid (NB, 4): block = (graph g, feature quarter fq). 1024 threads = 32 node-groups x 32 features.

__global__ __launch_bounds__(1024) void apply_readout_kernel(const float* __restrict__ y,
      const int* __restrict__ alive, const float* __restrict__ tanhv,
      float* __restrict__ x, float* __restrict__ h, int m){
  __shared__ float smx[32][33];
  __shared__ float ssm[32][33];
  int g = blockIdx.x;
  int fq = blockIdx.y;
  int t = threadIdx.x;
  int c  = t >> 5;         // node group 0..31
  int lf = t & 31;         // feature within quarter
  int f  = fq*32 + lf;
  int base = g*NPER;
  float mx = -INFINITY, sm = 0.f;
  #pragma unroll 4
  for (int i = 0; i < 32; ++i){
    int node = base + c + i*32;
    int al = alive[node];
    float tv = tanhv[node];           // garbage for dead nodes, never used
    float v = y[(size_t)node*128 + f];
    float o = al ? v*tv : 0.f;
    x[(size_t)node*128 + f] = o;
    mx = al ? fmaxf(mx, o) : mx;
    sm += o;
  }
  smx[c][lf] = mx; ssm[c][lf] = sm;
  __syncthreads();
  for (int s = 16; s > 0; s >>= 1){
    if (c < s){
      smx[c][lf] = fmaxf(smx[c][lf], smx[c+s][lf]);
      ssm[c][lf] += ssm[c+s][lf];
    }
    __syncthreads();
  }
  if (c == 0){
    h[g*256 + f]       += smx[0][lf];
    h[g*256 + 128 + f] += ssm[0][lf] / (float)m;
  }
}

// ---------------- final MLP + log_softmax ----------------

__global__ __launch_bounds__(128) void final_kernel(const float* __restrict__ h,
      const float* __restrict__ l1w, const float* __restrict__ l1b,
      const float* __restrict__ l2w, const float* __restrict__ l2b,
      float* __restrict__ out){
  int g = blockIdx.x, t = threadIdx.x;
  __shared__ float hrow[256];
  __shared__ float red0[128], red1[128];
  hrow[t]       = h[g*256 + t];
  hrow[t + 128] = h[g*256 + 128 + t];
  __syncthreads();
  float a = l1b[t];
  for (int k = 0; k < 256; ++k) a = fmaf(hrow[k], l1w[k*128 + t], a);
  a = fmaxf(a, 0.f);
  red0[t] = a * l2w[t*2 + 0];
  red1[t] = a * l2w[t*2 + 1];
  __syncthreads();
  for (int s = 64; s > 0; s >>= 1){
    if (t < s){ red0[t] += red0[t + s]; red1[t] += red1[t + s]; }
    __syncthreads();
  }
  if (t == 0){
    float z0 = fmaxf(red0[0] + l2b[0], 0.f);
    float z1 = fmaxf(red1[0] + l2b[1], 0.f);
    float mz = fmaxf(z0, z1);
    float lse = mz + logf(expf(z0 - mz) + expf(z1 - mz));
    out[g*2 + 0] = z0 - lse;
    out[g*2 + 1] = z1 - lse;
  }
}

// ---------------- host ----------------

static inline size_t alignup(size_t x){ return (x + 255) & ~(size_t)255; }

extern "C" void kernel_launch(void* const* d_in, const int* in_sizes, int n_in,
                              void* d_out, int out_size, void* d_ws, size_t ws_size,
                              hipStream_t stream) {
  const float* x_in = (const float*)d_in[0];
  const int*   ei   = (const int*)d_in[1];
  const float* Wr[3] = {(const float*)d_in[3], (const float*)d_in[6], (const float*)d_in[9]};
  const float* Wn[3] = {(const float*)d_in[4], (const float*)d_in[7], (const float*)d_in[10]};
  const float* bs[3] = {(const float*)d_in[5], (const float*)d_in[8], (const float*)d_in[11]};
  const float* ps[3] = {(const float*)d_in[12], (const float*)d_in[13], (const float*)d_in[14]};
  const float* l1w = (const float*)d_in[15];
  const float* l1b = (const float*)d_in[16];
  const float* l2w = (const float*)d_in[17];
  const float* l2b = (const float*)d_in[18];
  float* out = (float*)d_out;

  char* w = (char*)d_ws;
  size_t o = 0;
  auto take = [&](size_t bytes) -> void* { void* p = w + o; o = alignup(o + bytes); return p; };
  int*   off    = (int*)  take((size_t)(NN + 1) * 4);
  int*   adj    = (int*)  take((size_t)NE * 4);
  int*   cnt    = (int*)  take((size_t)NN * 4);
  int*   loc    = (int*)  take((size_t)NN * 4);
  int*   cursor = (int*)  take((size_t)NN * 4);
  int*   bsum   = (int*)  take(64 * 4);
  int*   boff   = (int*)  take(64 * 4);
  int*   aliveA = (int*)  take((size_t)NN * 4);
  int*   aliveB = (int*)  take((size_t)NN * 4);
  float* tanhv  = (float*)take((size_t)NN * 4);
  float* score  = (float*)take((size_t)NN * 4);
  float* h      = (float*)take((size_t)NB * 256 * 4);
  float* A      = (float*)take((size_t)NN * 128 * 4);  // node features (current level)
  float* Bb     = (float*)take((size_t)NN * 128 * 4);  // agg, then conv output y
  (void)ws_size; (void)n_in; (void)in_sizes; (void)out_size;

  // CSR build (by dst, storing src)
  hipMemsetAsync(cnt, 0, (size_t)NN * 4, stream);
  count_kernel<<<NE/256, 256, 0, stream>>>(ei, cnt);
  scan1_kernel<<<NN/1024, 1024, 0, stream>>>(cnt, loc, bsum);
  scan2_kernel<<<1, 64, 0, stream>>>(bsum, boff);
  scan3_kernel<<<NN/1024, 1024, 0, stream>>>(loc, boff, off, cursor);
  fill_kernel<<<NE/256, 256, 0, stream>>>(ei, cursor, adj);
  hipMemsetAsync(h, 0, (size_t)NB * 256 * 4, stream);

  const int MS[3] = {820, 656, 525};
  int* aliveCur = nullptr;
  int* aliveNext = aliveA;
  for (int l = 0; l < 3; ++l){
    if (l == 0){
      gather_kernel<<<NN*64/256, 256, 0, stream>>>(x_in, 64, 64, off, adj, Bb, nullptr);
      conv_kernel<<<NN/64, 256, 0, stream>>>(x_in, 64, 64, Wr[0], Bb, 64, Wn[0], bs[0], ps[0], Bb, score);
    } else {
      gather_kernel<<<NN*64/256, 256, 0, stream>>>(A, 128, 128, off, adj, Bb, aliveCur);
      conv_kernel<<<NN/64, 256, 0, stream>>>(A, 128, 128, Wr[l], Bb, 128, Wn[l], bs[l], ps[l], Bb, score);
    }
    topk_kernel<<<NB, 1024, 0, stream>>>(score, aliveCur, aliveNext, tanhv, ps[l], MS[l]);
    apply_readout_kernel<<<dim3(NB, 4), 1024, 0, stream>>>(Bb, aliveNext, tanhv, A, h, MS[l]);
    aliveCur = aliveNext;
    aliveNext = (l == 0) ? aliveB : aliveA;
  }
  final_kernel<<<NB, 128, 0, stream>>>(h, l1w, l1b, l2w, l2b, out);
}

// Round 4
// 572.674 us; speedup vs baseline: 2.3318x; 1.0827x over previous
//
#include <hip/hip_runtime.h>
#include <math.h>

#define NN   65536      // total nodes
#define NPER 1024       // nodes per graph
#define NE   1048576    // edges
#define NB   64         // graphs

// ---------------- CSR build ----------------

__global__ __launch_bounds__(256) void count_kernel(const int* __restrict__ ei, int* __restrict__ cnt){
  int e = blockIdx.x*256 + threadIdx.x;
  if (e < NE) atomicAdd(&cnt[ei[NE + e]], 1);
}

// hierarchical exclusive scan of cnt[NN] -> off[NN+1] (+ cursor copy)
__global__ __launch_bounds__(1024) void scan1_kernel(const int* __restrict__ cnt,
      int* __restrict__ loc, int* __restrict__ bsum){
  __shared__ int wsum[16];
  int t = threadIdx.x;
  int i = blockIdx.x*1024 + t;
  int lane = t & 63, wid = t >> 6;
  int v = cnt[i];
  int s = v;
  #pragma unroll
  for (int d = 1; d < 64; d <<= 1){
    int src = (lane >= d) ? (lane - d) : lane;
    int u = __shfl(s, src);
    if (lane >= d) s += u;
  }
  if (lane == 63) wsum[wid] = s;
  __syncthreads();
  if (wid == 0){
    int ws = (lane < 16) ? wsum[lane] : 0;
    #pragma unroll
    for (int d = 1; d < 16; d <<= 1){
      int src = (lane >= d) ? (lane - d) : lane;
      int u = __shfl(ws, src);
      if (lane >= d) ws += u;
    }
    if (lane < 16) wsum[lane] = ws;
  }
  __syncthreads();
  int base = (wid > 0) ? wsum[wid - 1] : 0;
  loc[i] = base + s - v;                 // exclusive within block
  if (t == 1023) bsum[blockIdx.x] = base + s;
}

__global__ __launch_bounds__(64) void scan2_kernel(const int* __restrict__ bsum, int* __restrict__ boff){
  int t = threadIdx.x;
  int v = bsum[t];
  int s = v;
  #pragma unroll
  for (int d = 1; d < 64; d <<= 1){
    int src = (t >= d) ? (t - d) : t;
    int u = __shfl(s, src);
    if (t >= d) s += u;
  }
  boff[t] = s - v;
}

__global__ __launch_bounds__(1024) void scan3_kernel(const int* __restrict__ loc, const int* __restrict__ boff,
      int* __restrict__ off, int* __restrict__ cursor){
  int i = blockIdx.x*1024 + threadIdx.x;
  int v = loc[i] + boff[blockIdx.x];
  off[i] = v;
  cursor[i] = v;
  if (i == NN - 1) off[NN] = NE;
}

__global__ __launch_bounds__(256) void fill_kernel(const int* __restrict__ ei, int* cursor, int* __restrict__ adj){
  int e = blockIdx.x*256 + threadIdx.x;
  if (e < NE){
    int pos = atomicAdd(&cursor[ei[NE + e]], 1);
    adj[pos] = ei[e];
  }
}

// ---------------- aggregation (segment_sum of x[src] into dst rows) ----------------

__global__ __launch_bounds__(256) void gather_kernel(const float* __restrict__ x, int stride, int F,
      const int* __restrict__ off, const int* __restrict__ adj, float* __restrict__ agg,
      const int* __restrict__ alive){
  int w = (blockIdx.x*256 + threadIdx.x) >> 6;
  int lane = threadIdx.x & 63;
  if (w >= NN) return;
  if (alive && !alive[w]) return;
  int s0 = off[w], s1 = off[w+1];
  if (F == 64){
    float a0 = 0.f;
    for (int e = s0; e < s1; ++e)
      a0 += x[(size_t)adj[e]*stride + lane];
    agg[(size_t)w*128 + lane] = a0;
  } else {
    float a0 = 0.f, a1 = 0.f;
    for (int e = s0; e < s1; ++e){
      float2 v = *(const float2*)(x + (size_t)adj[e]*stride + lane*2);
      a0 += v.x; a1 += v.y;
    }
    *(float2*)&agg[(size_t)w*128 + lane*2] = make_float2(a0, a1);
  }
}

// ---------------- conv: y = relu(x@Wr + agg@Wn + b), fused raw score = y . p ----------------
// 128 rows x 128 cols per block, 256 threads, thread = 8 rows (rlo, rlo+64) x 8 cols (clo, clo+64).
// LDS: xsT[kk][row] stride 140 (2-way staging writes, conflict-free b128 reads),
//      wsS[kk][col] stride 128 (2-way b128 reads). 2 FLOP per LDS byte.
// NOTE: yout aliases aggb: all global reads of agg rows happen during staging,
// before the final barrier; epilogue writes after.

__global__ __launch_bounds__(256) void conv_kernel(const float* __restrict__ xsrc, int strideX, int Kx,
      const float* __restrict__ Wr, const float* aggb, int Ka, const float* __restrict__ Wn,
      const float* __restrict__ bias, const float* __restrict__ p,
      float* yout, float* __restrict__ score){
  __shared__ float xsT[32*140];
  __shared__ float wsS[32*128];
  const int tid = threadIdx.x;
  const int row0 = blockIdx.x * 128;
  const int rq = tid >> 3;         // staging: row-quad 0..31
  const int kq = tid & 7;          // staging: k-quad 0..7
  const int rlo = (tid >> 4) * 4;  // compute rows rlo..+3, rlo+64..+67
  const int clo = (tid & 15) * 4;  // compute cols clo..+3, clo+64..+67
  float acc[2][2][4][4];
  #pragma unroll
  for (int i = 0; i < 2; ++i)
    #pragma unroll
    for (int j = 0; j < 2; ++j)
      #pragma unroll
      for (int r = 0; r < 4; ++r)
        #pragma unroll
        for (int c = 0; c < 4; ++c) acc[i][j][r][c] = 0.f;

  for (int phase = 0; phase < 2; ++phase){
    const float* X   = phase ? aggb : xsrc;
    const int stride = phase ? 128  : strideX;
    const int K      = phase ? Ka   : Kx;
    const float* W   = phase ? Wn   : Wr;
    for (int kc = 0; kc < K; kc += 32){
      __syncthreads();
      // stage X tile (128 rows x 32 k) transposed via 4x4 micro-blocks
      float4 xr[4];
      #pragma unroll
      for (int i = 0; i < 4; ++i)
        xr[i] = *(const float4*)&X[(size_t)(row0 + rq*4 + i)*stride + kc + kq*4];
      #pragma unroll
      for (int c = 0; c < 4; ++c){
        float4 t4;
        t4.x = ((const float*)&xr[0])[c];
        t4.y = ((const float*)&xr[1])[c];
        t4.z = ((const float*)&xr[2])[c];
        t4.w = ((const float*)&xr[3])[c];
        *(float4*)&xsT[(kq*4 + c)*140 + rq*4] = t4;
      }
      // stage W tile (32 k x 128 cols) linear
      #pragma unroll
      for (int t2 = 0; t2 < 4; ++t2){
        int idx4 = tid + t2*256;                 // float4 index 0..1023
        int kk = idx4 >> 5, col = (idx4 & 31) * 4;
        *(float4*)&wsS[kk*128 + col] = *(const float4*)&W[(size_t)(kc + kk)*128 + col];
      }
      __syncthreads();
      #pragma unroll 4
      for (int kk = 0; kk < 32; ++kk){
        float4 xv0 = *(const float4*)&xsT[kk*140 + rlo];
        float4 xv1 = *(const float4*)&xsT[kk*140 + rlo + 64];
        float4 wv0 = *(const float4*)&wsS[kk*128 + clo];
        float4 wv1 = *(const float4*)&wsS[kk*128 + clo + 64];
        const float* xv[2] = {(const float*)&xv0, (const float*)&xv1};
        const float* wv[2] = {(const float*)&wv0, (const float*)&wv1};
        #pragma unroll
        for (int i = 0; i < 2; ++i)
          #pragma unroll
          for (int r = 0; r < 4; ++r){
            float xvv = xv[i][r];
            #pragma unroll
            for (int j = 0; j < 2; ++j){
              #pragma unroll
              for (int c = 0; c < 4; ++c)
                acc[i][j][r][c] = fmaf(xvv, wv[j][c], acc[i][j][r][c]);
            }
          }
      }
    }
  }

  float4 bv0 = *(const float4*)&bias[clo];
  float4 bv1 = *(const float4*)&bias[clo + 64];
  float4 pv0 = *(const float4*)&p[clo];
  float4 pv1 = *(const float4*)&p[clo + 64];
  const float* bvp[2] = {(const float*)&bv0, (const float*)&bv1};
  const float* pvp[2] = {(const float*)&pv0, (const float*)&pv1};
  #pragma unroll
  for (int i = 0; i < 2; ++i)
    #pragma unroll
    for (int r = 0; r < 4; ++r){
      int row = row0 + rlo + i*64 + r;
      float part = 0.f;
      #pragma unroll
      for (int j = 0; j < 2; ++j){
        float4 o;
        o.x = fmaxf(acc[i][j][r][0] + bvp[j][0], 0.f);
        o.y = fmaxf(acc[i][j][r][1] + bvp[j][1], 0.f);
        o.z = fmaxf(acc[i][j][r][2] + bvp[j][2], 0.f);
        o.w = fmaxf(acc[i][j][r][3] + bvp[j][3], 0.f);
        *(float4*)&yout[(size_t)row*128 + clo + j*64] = o;
        part += o.x*pvp[j][0] + o.y*pvp[j][1] + o.z*pvp[j][2] + o.w*pvp[j][3];
      }
      #pragma unroll
      for (int m = 8; m >= 1; m >>= 1) part += __shfl_xor(part, m);
      if ((tid & 15) == 0) score[row] = part;
    }
}

// ---------------- per-graph top-k via bitonic sort of (raw score desc, idx asc) ----------------
// ordering is invariant to the positive scale 1/||p||; apply it only inside tanh.

__global__ __launch_bounds__(1024) void topk_kernel(const float* __restrict__ score, const int* __restrict__ alive_cur,
      int* __restrict__ alive_next, float* __restrict__ tanhv, const float* __restrict__ p, int m){
  __shared__ float sv[1024];
  __shared__ int   si[1024];
  __shared__ float rnorm;
  int g = blockIdx.x, t = threadIdx.x;
  if (t < 64){
    float v0 = p[t], v1 = p[t + 64];
    float ss = v0*v0 + v1*v1;
    #pragma unroll
    for (int mm = 32; mm >= 1; mm >>= 1) ss += __shfl_xor(ss, mm);
    if (t == 0) rnorm = rsqrtf(ss);
  }
  int node = g*NPER + t;
  bool ok = alive_cur ? (alive_cur[node] != 0) : true;
  sv[t] = ok ? score[node] : -INFINITY;
  si[t] = node;
  alive_next[node] = 0;
  __syncthreads();
  for (int size = 2; size <= 1024; size <<= 1){
    for (int stride = size >> 1; stride > 0; stride >>= 1){
      int j = t ^ stride;
      if (j > t){
        float vt = sv[t], vj = sv[j];
        int   it = si[t], ij = si[j];
        bool beforeTJ = (vt > vj) || (vt == vj && it < ij);  // t belongs first
        bool ascending = ((t & size) == 0);
        bool dosw = ascending ? !beforeTJ : beforeTJ;
        if (dosw){ sv[t] = vj; sv[j] = vt; si[t] = ij; si[j] = it; }
      }
      __syncthreads();
    }
  }
  if (t < m){
    int idx = si[t];
    alive_next[idx] = 1;
    tanhv[idx] = tanhf(sv[t] * rnorm);
  }
}

// ---------------- fused: x = selected ? y*tanh(s) : 0  +  per-graph masked max/mean readout ----------------

__global__ __launch_bounds__(1024) void apply_readout_kernel(const float* __restrict__ y,
      const int* __restrict__ alive, const float* __restrict__ tanhv,
      float* __restrict__ x, float* __restrict__ h, int m){
  __shared__ float smx[32][33];
  __shared__ float ssm[32][33];
  int g = blockIdx.x;
  int fq = blockIdx.y;
  int t = threadIdx.x;
  int c  = t >> 5;         // node group 0..31
  int lf = t & 31;         // feature within quarter
  int f  = fq*32 + lf;
  int base = g*NPER;
  float mx = -INFINITY, sm = 0.f;
  #pragma unroll 4
  for (int i = 0; i < 32; ++i){
    int node = base + c + i*32;
    int al = alive[node];
    float tv = tanhv[node];           // garbage for dead nodes, never used
    float v = y[(size_t)node*128 + f];
    float o = al ? v*tv : 0.f;
    x[(size_t)node*128 + f] = o;
    mx = al ? fmaxf(mx, o) : mx;
    sm += o;
  }
  smx[c][lf] = mx; ssm[c][lf] = sm;
  __syncthreads();
  for (int s = 16; s > 0; s >>= 1){
    if (c < s){
      smx[c][lf] = fmaxf(smx[c][lf], smx[c+s][lf]);
      ssm[c][lf] += ssm[c+s][lf];
    }
    __syncthreads();
  }
  if (c == 0){
    h[g*256 + f]       += smx[0][lf];
    h[g*256 + 128 + f] += ssm[0][lf] / (float)m;
  }
}

// ---------------- final MLP + log_softmax ----------------

__global__ __launch_bounds__(128) void final_kernel(const float* __restrict__ h,
      const float* __restrict__ l1w, const float* __restrict__ l1b,
      const float* __restrict__ l2w, const float* __restrict__ l2b,
      float* __restrict__ out){
  int g = blockIdx.x, t = threadIdx.x;
  __shared__ float hrow[256];
  __shared__ float red0[128], red1[128];
  hrow[t]       = h[g*256 + t];
  hrow[t + 128] = h[g*256 + 128 + t];
  __syncthreads();
  float a = l1b[t];
  for (int k = 0; k < 256; ++k) a = fmaf(hrow[k], l1w[k*128 + t], a);
  a = fmaxf(a, 0.f);
  red0[t] = a * l2w[t*2 + 0];
  red1[t] = a * l2w[t*2 + 1];
  __syncthreads();
  for (int s = 64; s > 0; s >>= 1){
    if (t < s){ red0[t] += red0[t + s]; red1[t] += red1[t + s]; }
    __syncthreads();
  }
  if (t == 0){
    float z0 = fmaxf(red0[0] + l2b[0], 0.f);
    float z1 = fmaxf(red1[0] + l2b[1], 0.f);
    float mz = fmaxf(z0, z1);
    float lse = mz + logf(expf(z0 - mz) + expf(z1 - mz));
    out[g*2 + 0] = z0 - lse;
    out[g*2 + 1] = z1 - lse;
  }
}

// ---------------- host ----------------

static inline size_t alignup(size_t x){ return (x + 255) & ~(size_t)255; }

extern "C" void kernel_launch(void* const* d_in, const int* in_sizes, int n_in,
                              void* d_out, int out_size, void* d_ws, size_t ws_size,
                              hipStream_t stream) {
  const float* x_in = (const float*)d_in[0];
  const int*   ei   = (const int*)d_in[1];
  const float* Wr[3] = {(const float*)d_in[3], (const float*)d_in[6], (const float*)d_in[9]};
  const float* Wn[3] = {(const float*)d_in[4], (const float*)d_in[7], (const float*)d_in[10]};
  const float* bs[3] = {(const float*)d_in[5], (const float*)d_in[8], (const float*)d_in[11]};
  const float* ps[3] = {(const float*)d_in[12], (const float*)d_in[13], (const float*)d_in[14]};
  const float* l1w = (const float*)d_in[15];
  const float* l1b = (const float*)d_in[16];
  const float* l2w = (const float*)d_in[17];
  const float* l2b = (const float*)d_in[18];
  float* out = (float*)d_out;

  char* w = (char*)d_ws;
  size_t o = 0;
  auto take = [&](size_t bytes) -> void* { void* p = w + o; o = alignup(o + bytes); return p; };
  int*   off    = (int*)  take((size_t)(NN + 1) * 4);
  int*   adj    = (int*)  take((size_t)NE * 4);
  int*   cnt    = (int*)  take((size_t)NN * 4);
  int*   loc    = (int*)  take((size_t)NN * 4);
  int*   cursor = (int*)  take((size_t)NN * 4);
  int*   bsum   = (int*)  take(64 * 4);
  int*   boff   = (int*)  take(64 * 4);
  int*   aliveA = (int*)  take((size_t)NN * 4);
  int*   aliveB = (int*)  take((size_t)NN * 4);
  float* tanhv  = (float*)take((size_t)NN * 4);
  float* score  = (float*)take((size_t)NN * 4);
  float* h      = (float*)take((size_t)NB * 256 * 4);
  float* A      = (float*)take((size_t)NN * 128 * 4);  // node features (current level)
  float* Bb     = (float*)take((size_t)NN * 128 * 4);  // agg, then conv output y
  (void)ws_size; (void)n_in; (void)in_sizes; (void)out_size;

  // CSR build (by dst, storing src)
  hipMemsetAsync(cnt, 0, (size_t)NN * 4, stream);
  count_kernel<<<NE/256, 256, 0, stream>>>(ei, cnt);
  scan1_kernel<<<NN/1024, 1024, 0, stream>>>(cnt, loc, bsum);
  scan2_kernel<<<1, 64, 0, stream>>>(bsum, boff);
  scan3_kernel<<<NN/1024, 1024, 0, stream>>>(loc, boff, off, cursor);
  fill_kernel<<<NE/256, 256, 0, stream>>>(ei, cursor, adj);
  hipMemsetAsync(h, 0, (size_t)NB * 256 * 4, stream);

  const int MS[3] = {820, 656, 525};
  int* aliveCur = nullptr;
  int* aliveNext = aliveA;
  for (int l = 0; l < 3; ++l){
    if (l == 0){
      gather_kernel<<<NN*64/256, 256, 0, stream>>>(x_in, 64, 64, off, adj, Bb, nullptr);
      conv_kernel<<<NN/128, 256, 0, stream>>>(x_in, 64, 64, Wr[0], Bb, 64, Wn[0], bs[0], ps[0], Bb, score);
    } else {
      gather_kernel<<<NN*64/256, 256, 0, stream>>>(A, 128, 128, off, adj, Bb, aliveCur);
      conv_kernel<<<NN/128, 256, 0, stream>>>(A, 128, 128, Wr[l], Bb, 128, Wn[l], bs[l], ps[l], Bb, score);
    }
    topk_kernel<<<NB, 1024, 0, stream>>>(score, aliveCur, aliveNext, tanhv, ps[l], MS[l]);
    apply_readout_kernel<<<dim3(NB, 4), 1024, 0, stream>>>(Bb, aliveNext, tanhv, A, h, MS[l]);
    aliveCur = aliveNext;
    aliveNext = (l == 0) ? aliveB : aliveA;
  }
  final_kernel<<<NB, 128, 0, stream>>>(h, l1w, l1b, l2w, l2b, out);
}

// Round 5
// 432.919 us; speedup vs baseline: 3.0846x; 1.3228x over previous
//
#include <hip/hip_runtime.h>
#include <math.h>

#define NN   65536      // total nodes
#define NPER 1024       // nodes per graph
#define NE   1048576    // edges
#define NB   64         // graphs

// ---------------- CSR build ----------------

__global__ __launch_bounds__(256) void count_kernel(const int* __restrict__ ei, int* __restrict__ cnt){
  int e = blockIdx.x*256 + threadIdx.x;
  if (e < NE) atomicAdd(&cnt[ei[NE + e]], 1);
}

// hierarchical exclusive scan of cnt[NN] -> off[NN+1] (+ cursor copy)
__global__ __launch_bounds__(1024) void scan1_kernel(const int* __restrict__ cnt,
      int* __restrict__ loc, int* __restrict__ bsum){
  __shared__ int wsum[16];
  int t = threadIdx.x;
  int i = blockIdx.x*1024 + t;
  int lane = t & 63, wid = t >> 6;
  int v = cnt[i];
  int s = v;
  #pragma unroll
  for (int d = 1; d < 64; d <<= 1){
    int src = (lane >= d) ? (lane - d) : lane;
    int u = __shfl(s, src);
    if (lane >= d) s += u;
  }
  if (lane == 63) wsum[wid] = s;
  __syncthreads();
  if (wid == 0){
    int ws = (lane < 16) ? wsum[lane] : 0;
    #pragma unroll
    for (int d = 1; d < 16; d <<= 1){
      int src = (lane >= d) ? (lane - d) : lane;
      int u = __shfl(ws, src);
      if (lane >= d) ws += u;
    }
    if (lane < 16) wsum[lane] = ws;
  }
  __syncthreads();
  int base = (wid > 0) ? wsum[wid - 1] : 0;
  loc[i] = base + s - v;                 // exclusive within block
  if (t == 1023) bsum[blockIdx.x] = base + s;
}

__global__ __launch_bounds__(64) void scan2_kernel(const int* __restrict__ bsum, int* __restrict__ boff){
  int t = threadIdx.x;
  int v = bsum[t];
  int s = v;
  #pragma unroll
  for (int d = 1; d < 64; d <<= 1){
    int src = (t >= d) ? (t - d) : t;
    int u = __shfl(s, src);
    if (t >= d) s += u;
  }
  boff[t] = s - v;
}

__global__ __launch_bounds__(1024) void scan3_kernel(const int* __restrict__ loc, const int* __restrict__ boff,
      int* __restrict__ off, int* __restrict__ cursor){
  int i = blockIdx.x*1024 + threadIdx.x;
  int v = loc[i] + boff[blockIdx.x];
  off[i] = v;
  cursor[i] = v;
  if (i == NN - 1) off[NN] = NE;
}

__global__ __launch_bounds__(256) void fill_kernel(const int* __restrict__ ei, int* cursor, int* __restrict__ adj){
  int e = blockIdx.x*256 + threadIdx.x;
  if (e < NE){
    int pos = atomicAdd(&cursor[ei[NE + e]], 1);
    adj[pos] = ei[e];
  }
}

// ---------------- aggregation (segment_sum of x[src] into dst rows) ----------------
// one wave per node, float4 per lane. F==64: 16 lanes/row -> 4 edge-groups, unroll x2
// (8 row-loads in flight). F==128: 32 lanes/row -> 2 edge-groups, unroll x4 (8 in flight).
// Cross-group shfl_xor reduce at the end. XCD-chunked block swizzle for L2 locality.

__global__ __launch_bounds__(256) void gather_kernel(const float* __restrict__ x, int stride, int F,
      const int* __restrict__ off, const int* __restrict__ adj, float* __restrict__ agg,
      const int* __restrict__ alive){
  int bid = blockIdx.x;
  bid = (bid & 7) * (gridDim.x >> 3) + (bid >> 3);   // round-robin XCD -> contiguous chunks
  int w = (bid*256 + (int)threadIdx.x) >> 6;
  int lane = threadIdx.x & 63;
  if (w >= NN) return;
  if (alive && !alive[w]) return;
  int s0 = off[w], s1 = off[w+1];
  if (F == 64){
    int sub = lane >> 4;            // edge-group 0..3
    int fl  = (lane & 15) * 4;      // features fl..fl+3
    float4 a0 = {0,0,0,0}, a1 = {0,0,0,0};
    for (int e = s0; e < s1; e += 8){
      int e0 = e + sub, e1 = e + 4 + sub;
      if (e0 < s1){
        float4 v = *(const float4*)&x[(size_t)adj[e0]*stride + fl];
        a0.x += v.x; a0.y += v.y; a0.z += v.z; a0.w += v.w;
      }
      if (e1 < s1){
        float4 v = *(const float4*)&x[(size_t)adj[e1]*stride + fl];
        a1.x += v.x; a1.y += v.y; a1.z += v.z; a1.w += v.w;
      }
    }
    a0.x += a1.x; a0.y += a1.y; a0.z += a1.z; a0.w += a1.w;
    #pragma unroll
    for (int m = 16; m <= 32; m <<= 1){
      a0.x += __shfl_xor(a0.x, m);
      a0.y += __shfl_xor(a0.y, m);
      a0.z += __shfl_xor(a0.z, m);
      a0.w += __shfl_xor(a0.w, m);
    }
    if (lane < 16) *(float4*)&agg[(size_t)w*128 + fl] = a0;
  } else {
    int sub = lane >> 5;            // edge-group 0..1
    int fl  = (lane & 31) * 4;
    float4 a0 = {0,0,0,0}, a1 = {0,0,0,0}, a2 = {0,0,0,0}, a3 = {0,0,0,0};
    for (int e = s0; e < s1; e += 8){
      int e0 = e + sub, e1 = e + 2 + sub, e2 = e + 4 + sub, e3 = e + 6 + sub;
      if (e0 < s1){
        float4 v = *(const float4*)&x[(size_t)adj[e0]*stride + fl];
        a0.x += v.x; a0.y += v.y; a0.z += v.z; a0.w += v.w;
      }
      if (e1 < s1){
        float4 v = *(const float4*)&x[(size_t)adj[e1]*stride + fl];
        a1.x += v.x; a1.y += v.y; a1.z += v.z; a1.w += v.w;
      }
      if (e2 < s1){
        float4 v = *(const float4*)&x[(size_t)adj[e2]*stride + fl];
        a2.x += v.x; a2.y += v.y; a2.z += v.z; a2.w += v.w;
      }
      if (e3 < s1){
        float4 v = *(const float4*)&x[(size_t)adj[e3]*stride + fl];
        a3.x += v.x; a3.y += v.y; a3.z += v.z; a3.w += v.w;
      }
    }
    a0.x += a1.x + a2.x + a3.x;
    a0.y += a1.y + a2.y + a3.y;
    a0.z += a1.z + a2.z + a3.z;
    a0.w += a1.w + a2.w + a3.w;
    a0.x += __shfl_xor(a0.x, 32);
    a0.y += __shfl_xor(a0.y, 32);
    a0.z += __shfl_xor(a0.z, 32);
    a0.w += __shfl_xor(a0.w, 32);
    if (lane < 32) *(float4*)&agg[(size_t)w*128 + fl] = a0;
  }
}

// ---------------- conv: y = relu(x@Wr + agg@Wn + b), fused raw score = y . p ----------------
// 128 rows x 128 cols per block, 256 threads, thread = 8 rows (rlo, rlo+64) x 8 cols (clo, clo+64).
// NOTE: yout aliases aggb: all global reads of agg rows happen during staging,
// before the final barrier; epilogue writes after.

__global__ __launch_bounds__(256) void conv_kernel(const float* __restrict__ xsrc, int strideX, int Kx,
      const float* __restrict__ Wr, const float* aggb, int Ka, const float* __restrict__ Wn,
      const float* __restrict__ bias, const float* __restrict__ p,
      float* yout, float* __restrict__ score){
  __shared__ float xsT[32*140];
  __shared__ float wsS[32*128];
  const int tid = threadIdx.x;
  const int row0 = blockIdx.x * 128;
  const int rq = tid >> 3;         // staging: row-quad 0..31
  const int kq = tid & 7;          // staging: k-quad 0..7
  const int rlo = (tid >> 4) * 4;  // compute rows rlo..+3, rlo+64..+67
  const int clo = (tid & 15) * 4;  // compute cols clo..+3, clo+64..+67
  float acc[2][2][4][4];
  #pragma unroll
  for (int i = 0; i < 2; ++i)
    #pragma unroll
    for (int j = 0; j < 2; ++j)
      #pragma unroll
      for (int r = 0; r < 4; ++r)
        #pragma unroll
        for (int c = 0; c < 4; ++c) acc[i][j][r][c] = 0.f;

  for (int phase = 0; phase < 2; ++phase){
    const float* X   = phase ? aggb : xsrc;
    const int stride = phase ? 128  : strideX;
    const int K      = phase ? Ka   : Kx;
    const float* W   = phase ? Wn   : Wr;
    for (int kc = 0; kc < K; kc += 32){
      __syncthreads();
      // stage X tile (128 rows x 32 k) transposed via 4x4 micro-blocks
      float4 xr[4];
      #pragma unroll
      for (int i = 0; i < 4; ++i)
        xr[i] = *(const float4*)&X[(size_t)(row0 + rq*4 + i)*stride + kc + kq*4];
      #pragma unroll
      for (int c = 0; c < 4; ++c){
        float4 t4;
        t4.x = ((const float*)&xr[0])[c];
        t4.y = ((const float*)&xr[1])[c];
        t4.z = ((const float*)&xr[2])[c];
        t4.w = ((const float*)&xr[3])[c];
        *(float4*)&xsT[(kq*4 + c)*140 + rq*4] = t4;
      }
      // stage W tile (32 k x 128 cols) linear
      #pragma unroll
      for (int t2 = 0; t2 < 4; ++t2){
        int idx4 = tid + t2*256;                 // float4 index 0..1023
        int kk = idx4 >> 5, col = (idx4 & 31) * 4;
        *(float4*)&wsS[kk*128 + col] = *(const float4*)&W[(size_t)(kc + kk)*128 + col];
      }
      __syncthreads();
      #pragma unroll 4
      for (int kk = 0; kk < 32; ++kk){
        float4 xv0 = *(const float4*)&xsT[kk*140 + rlo];
        float4 xv1 = *(const float4*)&xsT[kk*140 + rlo + 64];
        float4 wv0 = *(const float4*)&wsS[kk*128 + clo];
        float4 wv1 = *(const float4*)&wsS[kk*128 + clo + 64];
        const float* xv[2] = {(const float*)&xv0, (const float*)&xv1};
        const float* wv[2] = {(const float*)&wv0, (const float*)&wv1};
        #pragma unroll
        for (int i = 0; i < 2; ++i)
          #pragma unroll
          for (int r = 0; r < 4; ++r){
            float xvv = xv[i][r];
            #pragma unroll
            for (int j = 0; j < 2; ++j){
              #pragma unroll
              for (int c = 0; c < 4; ++c)
                acc[i][j][r][c] = fmaf(xvv, wv[j][c], acc[i][j][r][c]);
            }
          }
      }
    }
  }

  float4 bv0 = *(const float4*)&bias[clo];
  float4 bv1 = *(const float4*)&bias[clo + 64];
  float4 pv0 = *(const float4*)&p[clo];
  float4 pv1 = *(const float4*)&p[clo + 64];
  const float* bvp[2] = {(const float*)&bv0, (const float*)&bv1};
  const float* pvp[2] = {(const float*)&pv0, (const float*)&pv1};
  #pragma unroll
  for (int i = 0; i < 2; ++i)
    #pragma unroll
    for (int r = 0; r < 4; ++r){
      int row = row0 + rlo + i*64 + r;
      float part = 0.f;
      #pragma unroll
      for (int j = 0; j < 2; ++j){
        float4 o;
        o.x = fmaxf(acc[i][j][r][0] + bvp[j][0], 0.f);
        o.y = fmaxf(acc[i][j][r][1] + bvp[j][1], 0.f);
        o.z = fmaxf(acc[i][j][r][2] + bvp[j][2], 0.f);
        o.w = fmaxf(acc[i][j][r][3] + bvp[j][3], 0.f);
        *(float4*)&yout[(size_t)row*128 + clo + j*64] = o;
        part += o.x*pvp[j][0] + o.y*pvp[j][1] + o.z*pvp[j][2] + o.w*pvp[j][3];
      }
      #pragma unroll
      for (int m = 8; m >= 1; m >>= 1) part += __shfl_xor(part, m);
      if ((tid & 15) == 0) score[row] = part;
    }
}

// ---------------- per-graph top-k via bitonic sort of (raw score desc, idx asc) ----------------
// ordering is invariant to the positive scale 1/||p||; apply it only inside tanh.

__global__ __launch_bounds__(1024) void topk_kernel(const float* __restrict__ score, const int* __restrict__ alive_cur,
      int* __restrict__ alive_next, float* __restrict__ tanhv, const float* __restrict__ p, int m){
  __shared__ float sv[1024];
  __shared__ int   si[1024];
  __shared__ float rnorm;
  int g = blockIdx.x, t = threadIdx.x;
  if (t < 64){
    float v0 = p[t], v1 = p[t + 64];
    float ss = v0*v0 + v1*v1;
    #pragma unroll
    for (int mm = 32; mm >= 1; mm >>= 1) ss += __shfl_xor(ss, mm);
    if (t == 0) rnorm = rsqrtf(ss);
  }
  int node = g*NPER + t;
  bool ok = alive_cur ? (alive_cur[node] != 0) : true;
  sv[t] = ok ? score[node] : -INFINITY;
  si[t] = node;
  alive_next[node] = 0;
  __syncthreads();
  for (int size = 2; size <= 1024; size <<= 1){
    for (int stride = size >> 1; stride > 0; stride >>= 1){
      int j = t ^ stride;
      if (j > t){
        float vt = sv[t], vj = sv[j];
        int   it = si[t], ij = si[j];
        bool beforeTJ = (vt > vj) || (vt == vj && it < ij);  // t belongs first
        bool ascending = ((t & size) == 0);
        bool dosw = ascending ? !beforeTJ : beforeTJ;
        if (dosw){ sv[t] = vj; sv[j] = vt; si[t] = ij; si[j] = it; }
      }
      __syncthreads();
    }
  }
  if (t < m){
    int idx = si[t];
    alive_next[idx] = 1;
    tanhv[idx] = tanhf(sv[t] * rnorm);
  }
}

// ---------------- fused: x = selected ? y*tanh(s) : 0  +  per-graph masked max/mean readout ----------------

__global__ __launch_bounds__(1024) void apply_readout_kernel(const float* __restrict__ y,
      const int* __restrict__ alive, const float* __restrict__ tanhv,
      float* __restrict__ x, float* __restrict__ h, int m){
  __shared__ float smx[32][33];
  __shared__ float ssm[32][33];
  int g = blockIdx.x;
  int fq = blockIdx.y;
  int t = threadIdx.x;
  int c  = t >> 5;         // node group 0..31
  int lf = t & 31;         // feature within quarter
  int f  = fq*32 + lf;
  int base = g*NPER;
  float mx = -INFINITY, sm = 0.f;
  #pragma unroll 4
  for (int i = 0; i < 32; ++i){
    int node = base + c + i*32;
    int al = alive[node];
    float tv = tanhv[node];           // garbage for dead nodes, never used
    float v = y[(size_t)node*128 + f];
    float o = al ? v*tv : 0.f;
    x[(size_t)node*128 + f] = o;
    mx = al ? fmaxf(mx, o) : mx;
    sm += o;
  }
  smx[c][lf] = mx; ssm[c][lf] = sm;
  __syncthreads();
  for (int s = 16; s > 0; s >>= 1){
    if (c < s){
      smx[c][lf] = fmaxf(smx[c][lf], smx[c+s][lf]);
      ssm[c][lf] += ssm[c+s][lf];
    }
    __syncthreads();
  }
  if (c == 0){
    h[g*256 + f]       += smx[0][lf];
    h[g*256 + 128 + f] += ssm[0][lf] / (float)m;
  }
}

// ---------------- final MLP + log_softmax ----------------

__global__ __launch_bounds__(128) void final_kernel(const float* __restrict__ h,
      const float* __restrict__ l1w, const float* __restrict__ l1b,
      const float* __restrict__ l2w, const float* __restrict__ l2b,
      float* __restrict__ out){
  int g = blockIdx.x, t = threadIdx.x;
  __shared__ float hrow[256];
  __shared__ float red0[128], red1[128];
  hrow[t]       = h[g*256 + t];
  hrow[t + 128] = h[g*256 + 128 + t];
  __syncthreads();
  float a = l1b[t];
  for (int k = 0; k < 256; ++k) a = fmaf(hrow[k], l1w[k*128 + t], a);
  a = fmaxf(a, 0.f);
  red0[t] = a * l2w[t*2 + 0];
  red1[t] = a * l2w[t*2 + 1];
  __syncthreads();
  for (int s = 64; s > 0; s >>= 1){
    if (t < s){ red0[t] += red0[t + s]; red1[t] += red1[t + s]; }
    __syncthreads();
  }
  if (t == 0){
    float z0 = fmaxf(red0[0] + l2b[0], 0.f);
    float z1 = fmaxf(red1[0] + l2b[1], 0.f);
    float mz = fmaxf(z0, z1);
    float lse = mz + logf(expf(z0 - mz) + expf(z1 - mz));
    out[g*2 + 0] = z0 - lse;
    out[g*2 + 1] = z1 - lse;
  }
}

// ---------------- host ----------------

static inline size_t alignup(size_t x){ return (x + 255) & ~(size_t)255; }

extern "C" void kernel_launch(void* const* d_in, const int* in_sizes, int n_in,
                              void* d_out, int out_size, void* d_ws, size_t ws_size,
                              hipStream_t stream) {
  const float* x_in = (const float*)d_in[0];
  const int*   ei   = (const int*)d_in[1];
  const float* Wr[3] = {(const float*)d_in[3], (const float*)d_in[6], (const float*)d_in[9]};
  const float* Wn[3] = {(const float*)d_in[4], (const float*)d_in[7], (const float*)d_in[10]};
  const float* bs[3] = {(const float*)d_in[5], (const float*)d_in[8], (const float*)d_in[11]};
  const float* ps[3] = {(const float*)d_in[12], (const float*)d_in[13], (const float*)d_in[14]};
  const float* l1w = (const float*)d_in[15];
  const float* l1b = (const float*)d_in[16];
  const float* l2w = (const float*)d_in[17];
  const float* l2b = (const float*)d_in[18];
  float* out = (float*)d_out;

  char* w = (char*)d_ws;
  size_t o = 0;
  auto take = [&](size_t bytes) -> void* { void* p = w + o; o = alignup(o + bytes); return p; };
  int*   off    = (int*)  take((size_t)(NN + 1) * 4);
  int*   adj    = (int*)  take((size_t)NE * 4);
  int*   cnt    = (int*)  take((size_t)NN * 4);
  int*   loc    = (int*)  take((size_t)NN * 4);
  int*   cursor = (int*)  take((size_t)NN * 4);
  int*   bsum   = (int*)  take(64 * 4);
  int*   boff   = (int*)  take(64 * 4);
  int*   aliveA = (int*)  take((size_t)NN * 4);
  int*   aliveB = (int*)  take((size_t)NN * 4);
  float* tanhv  = (float*)take((size_t)NN * 4);
  float* score  = (float*)take((size_t)NN * 4);
  float* h      = (float*)take((size_t)NB * 256 * 4);
  float* A      = (float*)take((size_t)NN * 128 * 4);  // node features (current level)
  float* Bb     = (float*)take((size_t)NN * 128 * 4);  // agg, then conv output y
  (void)ws_size; (void)n_in; (void)in_sizes; (void)out_size;

  // CSR build (by dst, storing src)
  hipMemsetAsync(cnt, 0, (size_t)NN * 4, stream);
  count_kernel<<<NE/256, 256, 0, stream>>>(ei, cnt);
  scan1_kernel<<<NN/1024, 1024, 0, stream>>>(cnt, loc, bsum);
  scan2_kernel<<<1, 64, 0, stream>>>(bsum, boff);
  scan3_kernel<<<NN/1024, 1024, 0, stream>>>(loc, boff, off, cursor);
  fill_kernel<<<NE/256, 256, 0, stream>>>(ei, cursor, adj);
  hipMemsetAsync(h, 0, (size_t)NB * 256 * 4, stream);

  const int MS[3] = {820, 656, 525};
  int* aliveCur = nullptr;
  int* aliveNext = aliveA;
  for (int l = 0; l < 3; ++l){
    if (l == 0){
      gather_kernel<<<NN*64/256, 256, 0, stream>>>(x_in, 64, 64, off, adj, Bb, nullptr);
      conv_kernel<<<NN/128, 256, 0, stream>>>(x_in, 64, 64, Wr[0], Bb, 64, Wn[0], bs[0], ps[0], Bb, score);
    } else {
      gather_kernel<<<NN*64/256, 256, 0, stream>>>(A, 128, 128, off, adj, Bb, aliveCur);
      conv_kernel<<<NN/128, 256, 0, stream>>>(A, 128, 128, Wr[l], Bb, 128, Wn[l], bs[l], ps[l], Bb, score);
    }
    topk_kernel<<<NB, 1024, 0, stream>>>(score, aliveCur, aliveNext, tanhv, ps[l], MS[l]);
    apply_readout_kernel<<<dim3(NB, 4), 1024, 0, stream>>>(Bb, aliveNext, tanhv, A, h, MS[l]);
    aliveCur = aliveNext;
    aliveNext = (l == 0) ? aliveB : aliveA;
  }
  final_kernel<<<NB, 128, 0, stream>>>(h, l1w, l1b, l2w, l2b, out);
}

// Round 6
// 425.583 us; speedup vs baseline: 3.1378x; 1.0172x over previous
//
#include <hip/hip_runtime.h>
#include <math.h>

#define NN   65536      // total nodes
#define NPER 1024       // nodes per graph
#define NE   1048576    // edges
#define NB   64         // graphs

// ---------------- CSR build ----------------

__global__ __launch_bounds__(256) void count_kernel(const int* __restrict__ ei, int* __restrict__ cnt){
  int e = blockIdx.x*256 + threadIdx.x;
  if (e < NE) atomicAdd(&cnt[ei[NE + e]], 1);
}

// hierarchical exclusive scan of cnt[NN] -> off[NN+1] (+ cursor copy)
__global__ __launch_bounds__(1024) void scan1_kernel(const int* __restrict__ cnt,
      int* __restrict__ loc, int* __restrict__ bsum){
  __shared__ int wsum[16];
  int t = threadIdx.x;
  int i = blockIdx.x*1024 + t;
  int lane = t & 63, wid = t >> 6;
  int v = cnt[i];
  int s = v;
  #pragma unroll
  for (int d = 1; d < 64; d <<= 1){
    int src = (lane >= d) ? (lane - d) : lane;
    int u = __shfl(s, src);
    if (lane >= d) s += u;
  }
  if (lane == 63) wsum[wid] = s;
  __syncthreads();
  if (wid == 0){
    int ws = (lane < 16) ? wsum[lane] : 0;
    #pragma unroll
    for (int d = 1; d < 16; d <<= 1){
      int src = (lane >= d) ? (lane - d) : lane;
      int u = __shfl(ws, src);
      if (lane >= d) ws += u;
    }
    if (lane < 16) wsum[lane] = ws;
  }
  __syncthreads();
  int base = (wid > 0) ? wsum[wid - 1] : 0;
  loc[i] = base + s - v;                 // exclusive within block
  if (t == 1023) bsum[blockIdx.x] = base + s;
}

__global__ __launch_bounds__(64) void scan2_kernel(const int* __restrict__ bsum, int* __restrict__ boff){
  int t = threadIdx.x;
  int v = bsum[t];
  int s = v;
  #pragma unroll
  for (int d = 1; d < 64; d <<= 1){
    int src = (t >= d) ? (t - d) : t;
    int u = __shfl(s, src);
    if (t >= d) s += u;
  }
  boff[t] = s - v;
}

__global__ __launch_bounds__(1024) void scan3_kernel(const int* __restrict__ loc, const int* __restrict__ boff,
      int* __restrict__ off, int* __restrict__ cursor){
  int i = blockIdx.x*1024 + threadIdx.x;
  int v = loc[i] + boff[blockIdx.x];
  off[i] = v;
  cursor[i] = v;
  if (i == NN - 1) off[NN] = NE;
}

__global__ __launch_bounds__(256) void fill_kernel(const int* __restrict__ ei, int* cursor, int* __restrict__ adj){
  int e = blockIdx.x*256 + threadIdx.x;
  if (e < NE){
    int pos = atomicAdd(&cursor[ei[NE + e]], 1);
    adj[pos] = ei[e];
  }
}

// ---------------- aggregation (segment_sum of x[src] into dst rows) ----------------
// one wave per node, float4 per lane, 8 row-loads in flight, XCD-chunked swizzle.

__global__ __launch_bounds__(256) void gather_kernel(const float* __restrict__ x, int stride, int F,
      const int* __restrict__ off, const int* __restrict__ adj, float* __restrict__ agg,
      const int* __restrict__ alive){
  int bid = blockIdx.x;
  bid = (bid & 7) * (gridDim.x >> 3) + (bid >> 3);   // round-robin XCD -> contiguous chunks
  int w = (bid*256 + (int)threadIdx.x) >> 6;
  int lane = threadIdx.x & 63;
  if (w >= NN) return;
  if (alive && !alive[w]) return;
  int s0 = off[w], s1 = off[w+1];
  if (F == 64){
    int sub = lane >> 4;            // edge-group 0..3
    int fl  = (lane & 15) * 4;      // features fl..fl+3
    float4 a0 = {0,0,0,0}, a1 = {0,0,0,0};
    for (int e = s0; e < s1; e += 8){
      int e0 = e + sub, e1 = e + 4 + sub;
      if (e0 < s1){
        float4 v = *(const float4*)&x[(size_t)adj[e0]*stride + fl];
        a0.x += v.x; a0.y += v.y; a0.z += v.z; a0.w += v.w;
      }
      if (e1 < s1){
        float4 v = *(const float4*)&x[(size_t)adj[e1]*stride + fl];
        a1.x += v.x; a1.y += v.y; a1.z += v.z; a1.w += v.w;
      }
    }
    a0.x += a1.x; a0.y += a1.y; a0.z += a1.z; a0.w += a1.w;
    #pragma unroll
    for (int m = 16; m <= 32; m <<= 1){
      a0.x += __shfl_xor(a0.x, m);
      a0.y += __shfl_xor(a0.y, m);
      a0.z += __shfl_xor(a0.z, m);
      a0.w += __shfl_xor(a0.w, m);
    }
    if (lane < 16) *(float4*)&agg[(size_t)w*128 + fl] = a0;
  } else {
    int sub = lane >> 5;            // edge-group 0..1
    int fl  = (lane & 31) * 4;
    float4 a0 = {0,0,0,0}, a1 = {0,0,0,0}, a2 = {0,0,0,0}, a3 = {0,0,0,0};
    for (int e = s0; e < s1; e += 8){
      int e0 = e + sub, e1 = e + 2 + sub, e2 = e + 4 + sub, e3 = e + 6 + sub;
      if (e0 < s1){
        float4 v = *(const float4*)&x[(size_t)adj[e0]*stride + fl];
        a0.x += v.x; a0.y += v.y; a0.z += v.z; a0.w += v.w;
      }
      if (e1 < s1){
        float4 v = *(const float4*)&x[(size_t)adj[e1]*stride + fl];
        a1.x += v.x; a1.y += v.y; a1.z += v.z; a1.w += v.w;
      }
      if (e2 < s1){
        float4 v = *(const float4*)&x[(size_t)adj[e2]*stride + fl];
        a2.x += v.x; a2.y += v.y; a2.z += v.z; a2.w += v.w;
      }
      if (e3 < s1){
        float4 v = *(const float4*)&x[(size_t)adj[e3]*stride + fl];
        a3.x += v.x; a3.y += v.y; a3.z += v.z; a3.w += v.w;
      }
    }
    a0.x += a1.x + a2.x + a3.x;
    a0.y += a1.y + a2.y + a3.y;
    a0.z += a1.z + a2.z + a3.z;
    a0.w += a1.w + a2.w + a3.w;
    a0.x += __shfl_xor(a0.x, 32);
    a0.y += __shfl_xor(a0.y, 32);
    a0.z += __shfl_xor(a0.z, 32);
    a0.w += __shfl_xor(a0.w, 32);
    if (lane < 32) *(float4*)&agg[(size_t)w*128 + fl] = a0;
  }
}

// ---------------- conv: y = relu(x@Wr + agg@Wn + b), fused raw score = y . p ----------------
// 128x128 tile, 256 threads, 8x8 per thread. Register-prefetch pipeline over a flat
// tile stream (both GEMM phases): prefetch tile t+1's global loads before computing
// tile t, so HBM/L2 latency hides under 32 k-iters of FMA.
// xsT is XOR-swizzled: phys row-quad = (rq&24)|((rq+(kk>>2))&7) -> conflict-free
// micro-transpose writes AND conflict-free compute reads, no padding (32KB LDS total).
// NOTE: yout aliases aggb: the last agg prefetch completes (vmcnt) at the final LDS
// commit, before the epilogue writes.

__global__ __launch_bounds__(256) void conv_kernel(const float* __restrict__ xsrc, int strideX, int Kx,
      const float* __restrict__ Wr, const float* aggb, int Ka, const float* __restrict__ Wn,
      const float* __restrict__ bias, const float* __restrict__ p,
      float* yout, float* __restrict__ score){
  __shared__ float xsT[32*128];    // [kk][swizzled row]
  __shared__ float wsS[32*128];    // [kk][col]
  const int tid = threadIdx.x;
  const int row0 = blockIdx.x * 128;
  const int rq  = tid >> 3;        // staging: row-quad 0..31
  const int kq  = tid & 7;         // staging: k-quad 0..7
  const int physw = (rq & 24) | ((rq + kq) & 7);   // swizzled write block
  const int rb  = tid >> 4;        // compute: row block 0..15 (rows rb*4.., +64)
  const int clo = (tid & 15) * 4;  // compute cols clo..+3, clo+64..+67

  float acc[2][2][4][4];
  #pragma unroll
  for (int i = 0; i < 2; ++i)
    #pragma unroll
    for (int j = 0; j < 2; ++j)
      #pragma unroll
      for (int r = 0; r < 4; ++r)
        #pragma unroll
        for (int c = 0; c < 4; ++c) acc[i][j][r][c] = 0.f;

  const int nt0 = Kx >> 5, nt = nt0 + (Ka >> 5);
  float4 xr0, xr1, xr2, xr3, wq0, wq1, wq2, wq3;

  auto prefetch = [&](int t){
    const float* X; int stride; const float* W; int kc;
    if (t < nt0){ X = xsrc; stride = strideX; W = Wr;  kc = t*32; }
    else        { X = aggb; stride = 128;     W = Wn;  kc = (t - nt0)*32; }
    const float* xp = X + (size_t)(row0 + rq*4)*stride + kc + kq*4;
    xr0 = *(const float4*)(xp);
    xr1 = *(const float4*)(xp + stride);
    xr2 = *(const float4*)(xp + 2*stride);
    xr3 = *(const float4*)(xp + 3*stride);
    const float* wp = W + (size_t)kc*128 + (tid >> 5)*128 + (tid & 31)*4;
    wq0 = *(const float4*)(wp);
    wq1 = *(const float4*)(wp + 8*128);
    wq2 = *(const float4*)(wp + 16*128);
    wq3 = *(const float4*)(wp + 24*128);
  };

  prefetch(0);
  for (int t = 0; t < nt; ++t){
    __syncthreads();               // previous tile's compute done, LDS reusable
    // commit X (4x4 micro-transpose, swizzled) and W to LDS
    {
      const float* x0 = (const float*)&xr0;
      const float* x1 = (const float*)&xr1;
      const float* x2 = (const float*)&xr2;
      const float* x3 = (const float*)&xr3;
      #pragma unroll
      for (int c = 0; c < 4; ++c)
        *(float4*)&xsT[(kq*4 + c)*128 + physw*4] = make_float4(x0[c], x1[c], x2[c], x3[c]);
      float* wpS = &wsS[(tid >> 5)*128 + (tid & 31)*4];
      *(float4*)(wpS)          = wq0;
      *(float4*)(wpS + 8*128)  = wq1;
      *(float4*)(wpS + 16*128) = wq2;
      *(float4*)(wpS + 24*128) = wq3;
    }
    __syncthreads();
    if (t + 1 < nt) prefetch(t + 1);   // global loads in flight during compute
    #pragma unroll 8
    for (int kk = 0; kk < 32; ++kk){
      const int physr = (rb & 24) | ((rb + (kk >> 2)) & 7);
      const float4 xv0 = *(const float4*)&xsT[kk*128 + physr*4];
      const float4 xv1 = *(const float4*)&xsT[kk*128 + physr*4 + 64];
      const float4 wv0 = *(const float4*)&wsS[kk*128 + clo];
      const float4 wv1 = *(const float4*)&wsS[kk*128 + clo + 64];
      const float* xe0 = (const float*)&xv0;
      const float* xe1 = (const float*)&xv1;
      const float* we0 = (const float*)&wv0;
      const float* we1 = (const float*)&wv1;
      #pragma unroll
      for (int r = 0; r < 4; ++r){
        float a0 = xe0[r], a1 = xe1[r];
        #pragma unroll
        for (int c = 0; c < 4; ++c){
          acc[0][0][r][c] = fmaf(a0, we0[c], acc[0][0][r][c]);
          acc[0][1][r][c] = fmaf(a0, we1[c], acc[0][1][r][c]);
          acc[1][0][r][c] = fmaf(a1, we0[c], acc[1][0][r][c]);
          acc[1][1][r][c] = fmaf(a1, we1[c], acc[1][1][r][c]);
        }
      }
    }
  }

  float4 bv0 = *(const float4*)&bias[clo];
  float4 bv1 = *(const float4*)&bias[clo + 64];
  float4 pv0 = *(const float4*)&p[clo];
  float4 pv1 = *(const float4*)&p[clo + 64];
  const float* bvp[2] = {(const float*)&bv0, (const float*)&bv1};
  const float* pvp[2] = {(const float*)&pv0, (const float*)&pv1};
  #pragma unroll
  for (int i = 0; i < 2; ++i)
    #pragma unroll
    for (int r = 0; r < 4; ++r){
      int row = row0 + rb*4 + i*64 + r;
      float part = 0.f;
      #pragma unroll
      for (int j = 0; j < 2; ++j){
        float4 o;
        o.x = fmaxf(acc[i][j][r][0] + bvp[j][0], 0.f);
        o.y = fmaxf(acc[i][j][r][1] + bvp[j][1], 0.f);
        o.z = fmaxf(acc[i][j][r][2] + bvp[j][2], 0.f);
        o.w = fmaxf(acc[i][j][r][3] + bvp[j][3], 0.f);
        *(float4*)&yout[(size_t)row*128 + clo + j*64] = o;
        part += o.x*pvp[j][0] + o.y*pvp[j][1] + o.z*pvp[j][2] + o.w*pvp[j][3];
      }
      #pragma unroll
      for (int m = 8; m >= 1; m >>= 1) part += __shfl_xor(part, m);
      if ((tid & 15) == 0) score[row] = part;
    }
}

// ---------------- per-graph top-k via bitonic sort of (raw score desc, idx asc) ----------------
// ordering is invariant to the positive scale 1/||p||; apply it only inside tanh.

__global__ __launch_bounds__(1024) void topk_kernel(const float* __restrict__ score, const int* __restrict__ alive_cur,
      int* __restrict__ alive_next, float* __restrict__ tanhv, const float* __restrict__ p, int m){
  __shared__ float sv[1024];
  __shared__ int   si[1024];
  __shared__ float rnorm;
  int g = blockIdx.x, t = threadIdx.x;
  if (t < 64){
    float v0 = p[t], v1 = p[t + 64];
    float ss = v0*v0 + v1*v1;
    #pragma unroll
    for (int mm = 32; mm >= 1; mm >>= 1) ss += __shfl_xor(ss, mm);
    if (t == 0) rnorm = rsqrtf(ss);
  }
  int node = g*NPER + t;
  bool ok = alive_cur ? (alive_cur[node] != 0) : true;
  sv[t] = ok ? score[node] : -INFINITY;
  si[t] = node;
  alive_next[node] = 0;
  __syncthreads();
  for (int size = 2; size <= 1024; size <<= 1){
    for (int stride = size >> 1; stride > 0; stride >>= 1){
      int j = t ^ stride;
      if (j > t){
        float vt = sv[t], vj = sv[j];
        int   it = si[t], ij = si[j];
        bool beforeTJ = (vt > vj) || (vt == vj && it < ij);  // t belongs first
        bool ascending = ((t & size) == 0);
        bool dosw = ascending ? !beforeTJ : beforeTJ;
        if (dosw){ sv[t] = vj; sv[j] = vt; si[t] = ij; si[j] = it; }
      }
      __syncthreads();
    }
  }
  if (t < m){
    int idx = si[t];
    alive_next[idx] = 1;
    tanhv[idx] = tanhf(sv[t] * rnorm);
  }
}

// ---------------- fused: x = selected ? y*tanh(s) : 0  +  per-graph masked max/mean readout ----------------

__global__ __launch_bounds__(1024) void apply_readout_kernel(const float* __restrict__ y,
      const int* __restrict__ alive, const float* __restrict__ tanhv,
      float* __restrict__ x, float* __restrict__ h, int m){
  __shared__ float smx[32][33];
  __shared__ float ssm[32][33];
  int g = blockIdx.x;
  int fq = blockIdx.y;
  int t = threadIdx.x;
  int c  = t >> 5;         // node group 0..31
  int lf = t & 31;         // feature within quarter
  int f  = fq*32 + lf;
  int base = g*NPER;
  float mx = -INFINITY, sm = 0.f;
  #pragma unroll 4
  for (int i = 0; i < 32; ++i){
    int node = base + c + i*32;
    int al = alive[node];
    float tv = tanhv[node];           // garbage for dead nodes, never used
    float v = y[(size_t)node*128 + f];
    float o = al ? v*tv : 0.f;
    x[(size_t)node*128 + f] = o;
    mx = al ? fmaxf(mx, o) : mx;
    sm += o;
  }
  smx[c][lf] = mx; ssm[c][lf] = sm;
  __syncthreads();
  for (int s = 16; s > 0; s >>= 1){
    if (c < s){
      smx[c][lf] = fmaxf(smx[c][lf], smx[c+s][lf]);
      ssm[c][lf] += ssm[c+s][lf];
    }
    __syncthreads();
  }
  if (c == 0){
    h[g*256 + f]       += smx[0][lf];
    h[g*256 + 128 + f] += ssm[0][lf] / (float)m;
  }
}

// ---------------- final MLP + log_softmax ----------------

__global__ __launch_bounds__(128) void final_kernel(const float* __restrict__ h,
      const float* __restrict__ l1w, const float* __restrict__ l1b,
      const float* __restrict__ l2w, const float* __restrict__ l2b,
      float* __restrict__ out){
  int g = blockIdx.x, t = threadIdx.x;
  __shared__ float hrow[256];
  __shared__ float red0[128], red1[128];
  hrow[t]       = h[g*256 + t];
  hrow[t + 128] = h[g*256 + 128 + t];
  __syncthreads();
  float a = l1b[t];
  for (int k = 0; k < 256; ++k) a = fmaf(hrow[k], l1w[k*128 + t], a);
  a = fmaxf(a, 0.f);
  red0[t] = a * l2w[t*2 + 0];
  red1[t] = a * l2w[t*2 + 1];
  __syncthreads();
  for (int s = 64; s > 0; s >>= 1){
    if (t < s){ red0[t] += red0[t + s]; red1[t] += red1[t + s]; }
    __syncthreads();
  }
  if (t == 0){
    float z0 = fmaxf(red0[0] + l2b[0], 0.f);
    float z1 = fmaxf(red1[0] + l2b[1], 0.f);
    float mz = fmaxf(z0, z1);
    float lse = mz + logf(expf(z0 - mz) + expf(z1 - mz));
    out[g*2 + 0] = z0 - lse;
    out[g*2 + 1] = z1 - lse;
  }
}

// ---------------- host ----------------

static inline size_t alignup(size_t x){ return (x + 255) & ~(size_t)255; }

extern "C" void kernel_launch(void* const* d_in, const int* in_sizes, int n_in,
                              void* d_out, int out_size, void* d_ws, size_t ws_size,
                              hipStream_t stream) {
  const float* x_in = (const float*)d_in[0];
  const int*   ei   = (const int*)d_in[1];
  const float* Wr[3] = {(const float*)d_in[3], (const float*)d_in[6], (const float*)d_in[9]};
  const float* Wn[3] = {(const float*)d_in[4], (const float*)d_in[7], (const float*)d_in[10]};
  const float* bs[3] = {(const float*)d_in[5], (const float*)d_in[8], (const float*)d_in[11]};
  const float* ps[3] = {(const float*)d_in[12], (const float*)d_in[13], (const float*)d_in[14]};
  const float* l1w = (const float*)d_in[15];
  const float* l1b = (const float*)d_in[16];
  const float* l2w = (const float*)d_in[17];
  const float* l2b = (const float*)d_in[18];
  float* out = (float*)d_out;

  char* w = (char*)d_ws;
  size_t o = 0;
  auto take = [&](size_t bytes) -> void* { void* p = w + o; o = alignup(o + bytes); return p; };
  int*   off    = (int*)  take((size_t)(NN + 1) * 4);
  int*   adj    = (int*)  take((size_t)NE * 4);
  int*   cnt    = (int*)  take((size_t)NN * 4);
  int*   loc    = (int*)  take((size_t)NN * 4);
  int*   cursor = (int*)  take((size_t)NN * 4);
  int*   bsum   = (int*)  take(64 * 4);
  int*   boff   = (int*)  take(64 * 4);
  int*   aliveA = (int*)  take((size_t)NN * 4);
  int*   aliveB = (int*)  take((size_t)NN * 4);
  float* tanhv  = (float*)take((size_t)NN * 4);
  float* score  = (float*)take((size_t)NN * 4);
  float* h      = (float*)take((size_t)NB * 256 * 4);
  float* A      = (float*)take((size_t)NN * 128 * 4);  // node features (current level)
  float* Bb     = (float*)take((size_t)NN * 128 * 4);  // agg, then conv output y
  (void)ws_size; (void)n_in; (void)in_sizes; (void)out_size;

  // CSR build (by dst, storing src)
  hipMemsetAsync(cnt, 0, (size_t)NN * 4, stream);
  count_kernel<<<NE/256, 256, 0, stream>>>(ei, cnt);
  scan1_kernel<<<NN/1024, 1024, 0, stream>>>(cnt, loc, bsum);
  scan2_kernel<<<1, 64, 0, stream>>>(bsum, boff);
  scan3_kernel<<<NN/1024, 1024, 0, stream>>>(loc, boff, off, cursor);
  fill_kernel<<<NE/256, 256, 0, stream>>>(ei, cursor, adj);
  hipMemsetAsync(h, 0, (size_t)NB * 256 * 4, stream);

  const int MS[3] = {820, 656, 525};
  int* aliveCur = nullptr;
  int* aliveNext = aliveA;
  for (int l = 0; l < 3; ++l){
    if (l == 0){
      gather_kernel<<<NN*64/256, 256, 0, stream>>>(x_in, 64, 64, off, adj, Bb, nullptr);
      conv_kernel<<<NN/128, 256, 0, stream>>>(x_in, 64, 64, Wr[0], Bb, 64, Wn[0], bs[0], ps[0], Bb, score);
    } else {
      gather_kernel<<<NN*64/256, 256, 0, stream>>>(A, 128, 128, off, adj, Bb, aliveCur);
      conv_kernel<<<NN/128, 256, 0, stream>>>(A, 128, 128, Wr[l], Bb, 128, Wn[l], bs[l], ps[l], Bb, score);
    }
    topk_kernel<<<NB, 1024, 0, stream>>>(score, aliveCur, aliveNext, tanhv, ps[l], MS[l]);
    apply_readout_kernel<<<dim3(NB, 4), 1024, 0, stream>>>(Bb, aliveNext, tanhv, A, h, MS[l]);
    aliveCur = aliveNext;
    aliveNext = (l == 0) ? aliveB : aliveA;
  }
  final_kernel<<<NB, 128, 0, stream>>>(h, l1w, l1b, l2w, l2b, out);
}